// Round 3
// baseline (1121.096 us; speedup 1.0000x reference)
//
#include <hip/hip_runtime.h>
#include <stdint.h>
#include <stddef.h>

// RRT/Nystrom attention, MI355X gfx950.
// Inputs/outputs FLOAT32. Heavy GEMMs: bf16 MFMA + fp32 accumulate,
// staged via global_load_lds (width 16) into linear LDS (m97 structure).
// Moore-Penrose chain: split-bf16 (hi/lo planes) MFMA ~ fp32-grade precision.
//   All chain matrices (A, W2, W3) are symmetric (polynomials of the symmetric
//   A0 = s*attn2@attn2^T), so the MFMA B-operand reads rows of the same buffer
//   -> no transpose staging, no LDS, no barriers in pgemm; 16x32 per wave for
//   occupancy (4-8 waves/SIMD).
// Softmaxes computed WITHOUT max-subtraction: scores are O(1) by construction
// (q scaled by d^-0.5; landmark means), exp() safely in fp32 range.
// attn1/attn3: swapped-QK^T (mfma(K,Q)) keeps each P-row lane-local; PV
// A-fragment built in-register via the k-slot permutation
// slot(ko,lq,j) -> m = (2ko+(j>>2))*16 + lq*4 + (j&3). attn1 is chunk-pipelined.

typedef __bf16 bf16x8 __attribute__((ext_vector_type(8)));
typedef __bf16 bf16x4 __attribute__((ext_vector_type(4)));
typedef float f32x4 __attribute__((ext_vector_type(4)));

__device__ __forceinline__ f32x4 mfma_bf16(bf16x8 a, bf16x8 b, f32x4 c) {
    return __builtin_amdgcn_mfma_f32_16x16x32_bf16(a, b, c, 0, 0, 0);
}

__device__ __forceinline__ void gload16(const __bf16* g, __bf16* l) {
    __builtin_amdgcn_global_load_lds(
        (const __attribute__((address_space(1))) void*)g,
        (__attribute__((address_space(3))) void*)l, 16, 0, 0);
}

// ---------------- init ----------------
__global__ void k_init_stats(float* stats) { stats[0] = 1.f; stats[1] = 0.f; }

// ---------------- x f32 -> bf16 (row-major copy) ----------------
__global__ __launch_bounds__(256) void k_cvt(const float* __restrict__ in,
        __bf16* __restrict__ out) {
    size_t base = ((size_t)blockIdx.x * 256 + threadIdx.x) * 8;
    float4 a = *(const float4*)&in[base];
    float4 b = *(const float4*)&in[base + 4];
    bf16x8 o;
    o[0] = (__bf16)a.x; o[1] = (__bf16)a.y; o[2] = (__bf16)a.z; o[3] = (__bf16)a.w;
    o[4] = (__bf16)b.x; o[5] = (__bf16)b.y; o[6] = (__bf16)b.z; o[7] = (__bf16)b.w;
    *(bf16x8*)&out[base] = o;
}

// ---------------- f32 -> bf16 transposed copy (weights), 64x64 tiles ----------------
__global__ __launch_bounds__(256) void k_transpose_f32(const float* __restrict__ in,
        __bf16* __restrict__ out, int R, int C) {
    __shared__ __bf16 tile[64 * 72];
    int r0 = blockIdx.x * 64, c0 = blockIdx.y * 64;
    int tid = threadIdx.x;
    #pragma unroll
    for (int i = 0; i < 16; ++i) {
        int slot = i * 256 + tid;
        int rr = slot >> 6, cc = slot & 63;
        tile[rr * 72 + cc] = (__bf16)in[(size_t)(r0 + rr) * C + c0 + cc];
    }
    __syncthreads();
    #pragma unroll
    for (int i = 0; i < 2; ++i) {
        int slot = i * 256 + tid;
        int cc = slot >> 3, s = slot & 7;
        bf16x8 t;
        #pragma unroll
        for (int j = 0; j < 8; ++j) t[j] = tile[(s * 8 + j) * 72 + cc];
        *(bf16x8*)&out[(size_t)(c0 + cc) * R + r0 + s * 8] = t;
    }
}

// ---------------- bf16 transpose, 64x64 tiles (for v -> vt) ----------------
__global__ __launch_bounds__(256) void k_transpose_bf(const __bf16* __restrict__ in,
        __bf16* __restrict__ out, int R, int C, long bsi, long bso) {
    __shared__ __bf16 tile[64 * 72];
    in  += (size_t)blockIdx.z * bsi;
    out += (size_t)blockIdx.z * bso;
    int r0 = blockIdx.x * 64, c0 = blockIdx.y * 64;
    int tid = threadIdx.x;
    #pragma unroll
    for (int i = 0; i < 2; ++i) {
        int slot = i * 256 + tid;
        int rr = slot >> 3, s = slot & 7;
        *(bf16x8*)&tile[rr * 72 + s * 8] =
            *(const bf16x8*)&in[(size_t)(r0 + rr) * C + c0 + s * 8];
    }
    __syncthreads();
    #pragma unroll
    for (int i = 0; i < 2; ++i) {
        int slot = i * 256 + tid;
        int cc = slot >> 3, s = slot & 7;
        bf16x8 t;
        #pragma unroll
        for (int j = 0; j < 8; ++j) t[j] = tile[(s * 8 + j) * 72 + cc];
        *(bf16x8*)&out[(size_t)(c0 + cc) * R + r0 + s * 8] = t;
    }
}

// ---------------- big GEMM: C = A(MxK,bf16) @ Bt(NxK,bf16)^T ----------------
// 128x128 tile, BK=64, global_load_lds(16B) staging into linear LDS.
template<int MODE>
__global__ __launch_bounds__(256) void k_gemm_big(const __bf16* __restrict__ A,
        const __bf16* __restrict__ Bt, int K,
        __bf16* __restrict__ qp, __bf16* __restrict__ kp, __bf16* __restrict__ vp,
        float* __restrict__ outp, const float* __restrict__ bias) {
    __shared__ __bf16 sA[128 * 64];
    __shared__ __bf16 sB[128 * 64];
    int tid = threadIdx.x;
    int wave = tid >> 6, l = tid & 63, lm = l & 15, lq = l >> 4;
    int wm = wave & 1, wn = wave >> 1;
    int m0 = blockIdx.x * 128, n0 = blockIdx.y * 128;
    int lr = l >> 3, lc = (l & 7) * 8;   // staging: lane -> row (of 8), col (of 64)
    f32x4 acc[4][4] = {};
    for (int k0 = 0; k0 < K; k0 += 64) {
        #pragma unroll
        for (int i = 0; i < 4; ++i) {
            int g = wave * 4 + i;        // 8-row group
            gload16(&A[(size_t)(m0 + g * 8 + lr) * K + k0 + lc], &sA[g * 512]);
        }
        #pragma unroll
        for (int i = 0; i < 4; ++i) {
            int g = wave * 4 + i;
            gload16(&Bt[(size_t)(n0 + g * 8 + lr) * K + k0 + lc], &sB[g * 512]);
        }
        __syncthreads();
        #pragma unroll
        for (int ko = 0; ko < 2; ++ko) {
            bf16x8 af[4], bfr[4];
            #pragma unroll
            for (int mi = 0; mi < 4; ++mi)
                af[mi] = *(bf16x8*)&sA[(wm * 64 + mi * 16 + lm) * 64 + ko * 32 + lq * 8];
            #pragma unroll
            for (int ni = 0; ni < 4; ++ni)
                bfr[ni] = *(bf16x8*)&sB[(wn * 64 + ni * 16 + lm) * 64 + ko * 32 + lq * 8];
            #pragma unroll
            for (int mi = 0; mi < 4; ++mi)
                #pragma unroll
                for (int ni = 0; ni < 4; ++ni)
                    acc[mi][ni] = mfma_bf16(af[mi], bfr[ni], acc[mi][ni]);
        }
        __syncthreads();
    }
    #pragma unroll
    for (int mi = 0; mi < 4; ++mi)
    #pragma unroll
    for (int ni = 0; ni < 4; ++ni)
    #pragma unroll
    for (int reg = 0; reg < 4; ++reg) {
        int gr = m0 + wm * 64 + mi * 16 + lq * 4 + reg;
        int gc = n0 + wn * 64 + ni * 16 + lm;
        float v = acc[mi][ni][reg];
        if (MODE == 0) {
            int which = gc >> 9, rem = gc & 511;
            int h = rem >> 6, d = rem & 63;
            int b = gr >> 13, tok = gr & 8191;
            size_t dst = ((size_t)((b * 8 + h) * 8192 + tok)) * 64 + d;
            if (which == 0)      qp[dst] = (__bf16)(v * 0.125f);
            else if (which == 1) kp[dst] = (__bf16)v;
            else                 vp[dst] = (__bf16)v;
        } else {
            outp[(size_t)gr * 512 + gc] = v + bias[gc];
        }
    }
}

// ---------------- landmark means (q_l, k_l) ----------------
__global__ __launch_bounds__(256) void k_landmarks(const __bf16* __restrict__ q,
        const __bf16* __restrict__ k, __bf16* __restrict__ ql, __bf16* __restrict__ kl) {
    int idx = blockIdx.x * 256 + threadIdx.x;
    int sel = idx >> 19;
    int rem = idx & 524287;
    int bh = rem >> 14;
    int m  = (rem >> 6) & 255;
    int d  = rem & 63;
    const __bf16* src = sel ? k : q;
    __bf16* dst = sel ? kl : ql;
    const __bf16* p = src + ((size_t)(bh * 8192 + m * 32)) * 64 + d;
    float s = 0.f;
    #pragma unroll
    for (int j = 0; j < 32; ++j) s += (float)p[j * 64];
    dst[(size_t)bh * 16384 + m * 64 + d] = (__bf16)(s * (1.f / 32.f));
}

// ---------------- attn2 = softmax(q_l @ k_l^T), hi/lo bf16 planes ----------------
__global__ __launch_bounds__(256) void k_attn2(const __bf16* __restrict__ ql,
        const __bf16* __restrict__ kl, __bf16* __restrict__ ph, __bf16* __restrict__ pl) {
    int tid = threadIdx.x;
    int wave = tid >> 6, l = tid & 63, lm = l & 15, lq = l >> 4;
    int bh = blockIdx.y;
    int r0 = blockIdx.x * 64 + wave * 16;
    const __bf16* qb = ql + (size_t)bh * 16384;
    const __bf16* kb = kl + (size_t)bh * 16384;
    bf16x8 af[2];
    #pragma unroll
    for (int ko = 0; ko < 2; ++ko)
        af[ko] = *(const bf16x8*)&qb[(size_t)(r0 + lm) * 64 + ko * 32 + lq * 8];
    f32x4 S[16] = {};
    #pragma unroll
    for (int ci = 0; ci < 16; ++ci)
        #pragma unroll
        for (int ko = 0; ko < 2; ++ko) {
            bf16x8 bfr = *(const bf16x8*)&kb[(size_t)(ci * 16 + lm) * 64 + ko * 32 + lq * 8];
            S[ci] = mfma_bf16(af[ko], bfr, S[ci]);
        }
    __bf16* oh = ph + (size_t)bh * 65536;
    __bf16* ol = pl + (size_t)bh * 65536;
    #pragma unroll
    for (int reg = 0; reg < 4; ++reg) {
        float sum = 0.f;
        #pragma unroll
        for (int ci = 0; ci < 16; ++ci) {
            float e = __expf(S[ci][reg]); S[ci][reg] = e; sum += e;
        }
        #pragma unroll
        for (int msk = 1; msk < 16; msk <<= 1) sum += __shfl_xor(sum, msk);
        float inv = 1.f / sum;
        int row = r0 + lq * 4 + reg;
        #pragma unroll
        for (int ci = 0; ci < 16; ++ci) {
            float v = S[ci][reg] * inv;
            __bf16 hh = (__bf16)v;
            oh[(size_t)row * 256 + ci * 16 + lm] = hh;
            ol[(size_t)row * 256 + ci * 16 + lm] = (__bf16)(v - (float)hh);
        }
    }
}

// ---------------- max col-sum of attn2 (row-sums are exactly 1) ----------------
__global__ __launch_bounds__(256) void k_stats(const __bf16* __restrict__ ph,
        const __bf16* __restrict__ pl, float* stats) {
    __shared__ float red[256];
    int tid = threadIdx.x;
    const __bf16* a = ph + (size_t)blockIdx.x * 65536;
    const __bf16* b = pl + (size_t)blockIdx.x * 65536;
    float cs = 0.f;
    for (int r = 0; r < 256; ++r)
        cs += (float)a[r * 256 + tid] + (float)b[r * 256 + tid];
    red[tid] = cs; __syncthreads();
    for (int off = 128; off > 0; off >>= 1) {
        if (tid < off) red[tid] = fmaxf(red[tid], red[tid + off]);
        __syncthreads();
    }
    if (tid == 0) atomicMax((int*)&stats[1], __float_as_int(red[0]));
}

// ---------------- z0 = attn2^T / colsum_max, hi/lo planes ----------------
__global__ __launch_bounds__(256) void k_z0(const __bf16* __restrict__ ph,
        const __bf16* __restrict__ pl, const float* __restrict__ stats,
        __bf16* __restrict__ zh, __bf16* __restrict__ zl) {
    int idx = blockIdx.x * 256 + threadIdx.x;
    int bh = idx >> 16, r = (idx >> 8) & 255, c = idx & 255;
    float inv = 1.f / (stats[0] * stats[1]);
    size_t src = ((size_t)bh << 16) + (size_t)c * 256 + r;
    float v = ((float)ph[src] + (float)pl[src]) * inv;
    __bf16 hh = (__bf16)v;
    zh[idx] = hh;
    zl[idx] = (__bf16)(v - (float)hh);
}

// ---------------- pinv GEMM core: LDS-free, barrier-free, hi/lo plane operands ----
// 16x32 per wave (1 m-frag x 2 n-frags), block tile 32x64, for occupancy.
__device__ __forceinline__ void pgemm_core(const __bf16* __restrict__ Ah,
        const __bf16* __restrict__ Al, const __bf16* __restrict__ Bth,
        const __bf16* __restrict__ Btl, int m0, int n0, f32x4 acc[2]) {
    int tid = threadIdx.x;
    int wave = tid >> 6, l = tid & 63, lm = l & 15, lq = l >> 4;
    int wm = wave & 1, wn = wave >> 1;
    size_t ra = (size_t)(m0 + wm * 16 + lm) * 256;
    size_t rb = (size_t)(n0 + wn * 32 + lm) * 256;
    #pragma unroll
    for (int ko = 0; ko < 8; ++ko) {
        int kk = ko * 32 + lq * 8;
        bf16x8 a_h = *(const bf16x8*)&Ah[ra + kk];
        bf16x8 a_l = *(const bf16x8*)&Al[ra + kk];
        bf16x8 b_h[2], b_l[2];
        #pragma unroll
        for (int ni = 0; ni < 2; ++ni) {
            b_h[ni] = *(const bf16x8*)&Bth[rb + ni * 4096 + kk];
            b_l[ni] = *(const bf16x8*)&Btl[rb + ni * 4096 + kk];
        }
        #pragma unroll
        for (int ni = 0; ni < 2; ++ni) {
            acc[ni] = mfma_bf16(a_h, b_h[ni], acc[ni]);
            acc[ni] = mfma_bf16(a_h, b_l[ni], acc[ni]);
            acc[ni] = mfma_bf16(a_l, b_h[ni], acc[ni]);
        }
    }
}

// Out = delta*I + alpha'*(A@B) + beta*Cin, alpha' = alpha/(s0*s1) if sPtr.
// outMode 0: hi/lo planes; outMode 1: bf16 slot-permuted zt2t.
// grid: (8, N/64, 32), block 256.
__global__ __launch_bounds__(256) void k_pgemm(const __bf16* __restrict__ Ah,
        const __bf16* __restrict__ Al, const __bf16* __restrict__ Bth,
        const __bf16* __restrict__ Btl, const __bf16* __restrict__ Ch,
        const __bf16* __restrict__ Cl, __bf16* __restrict__ OutH,
        __bf16* __restrict__ OutL, float alpha, const float* __restrict__ sPtr,
        float beta, float delta, int outMode, long bStride) {
    int tid = threadIdx.x;
    int wave = tid >> 6, l = tid & 63, lm = l & 15, lq = l >> 4;
    int wm = wave & 1, wn = wave >> 1;
    int bh = blockIdx.z;
    int m0 = blockIdx.x * 32, n0 = blockIdx.y * 64;
    float aEff = alpha;
    if (sPtr) aEff *= 1.f / (sPtr[0] * sPtr[1]);
    f32x4 acc[2] = {};
    pgemm_core(Ah + (size_t)bh * 65536, Al + (size_t)bh * 65536,
               Bth + (size_t)bh * bStride, Btl + (size_t)bh * bStride,
               m0, n0, acc);
    #pragma unroll
    for (int ni = 0; ni < 2; ++ni)
    #pragma unroll
    for (int reg = 0; reg < 4; ++reg) {
        int gr = m0 + wm * 16 + lq * 4 + reg;
        int gc = n0 + wn * 32 + ni * 16 + lm;
        float v = aEff * acc[ni][reg];
        if (beta != 0.f) {
            size_t ci = (size_t)bh * 65536 + (size_t)gr * 256 + gc;
            v += beta * ((float)Ch[ci] + (float)Cl[ci]);
        }
        if (gr == gc) v += delta;
        if (outMode == 0) {
            size_t di = (size_t)bh * 65536 + (size_t)gr * 256 + gc;
            __bf16 hh = (__bf16)v;
            OutH[di] = hh;
            OutL[di] = (__bf16)(v - (float)hh);
        } else {
            int ci2 = gr >> 4, lqm = (gr >> 2) & 3, r = gr & 3;
            int slot = ((ci2 >> 1) << 5) + (lqm << 3) + ((ci2 & 1) << 2) + r;
            OutH[(size_t)bh * 16384 + (size_t)gc * 256 + slot] = (__bf16)v;
        }
    }
}

// dual update: z' = 0.25 z@W3 (z<32) and A' = 0.25 A@W3 (z>=32), hi/lo planes
__global__ __launch_bounds__(256) void k_pgemm_dual(const __bf16* __restrict__ Zh,
        const __bf16* __restrict__ Zl, const __bf16* __restrict__ A2h,
        const __bf16* __restrict__ A2l, const __bf16* __restrict__ Bth,
        const __bf16* __restrict__ Btl, __bf16* __restrict__ OzH,
        __bf16* __restrict__ OzL, __bf16* __restrict__ OaH, __bf16* __restrict__ OaL) {
    int tid = threadIdx.x;
    int wave = tid >> 6, l = tid & 63, lm = l & 15, lq = l >> 4;
    int wm = wave & 1, wn = wave >> 1;
    int zz = blockIdx.z, bh = zz & 31;
    const __bf16* Lh = (zz >= 32 ? A2h : Zh) + (size_t)bh * 65536;
    const __bf16* Ll = (zz >= 32 ? A2l : Zl) + (size_t)bh * 65536;
    __bf16* Oh = (zz >= 32 ? OaH : OzH) + (size_t)bh * 65536;
    __bf16* Ol = (zz >= 32 ? OaL : OzL) + (size_t)bh * 65536;
    int m0 = blockIdx.x * 32, n0 = blockIdx.y * 64;
    f32x4 acc[2] = {};
    pgemm_core(Lh, Ll, Bth + (size_t)bh * 65536, Btl + (size_t)bh * 65536, m0, n0, acc);
    #pragma unroll
    for (int ni = 0; ni < 2; ++ni)
    #pragma unroll
    for (int reg = 0; reg < 4; ++reg) {
        int gr = m0 + wm * 16 + lq * 4 + reg;
        int gc = n0 + wn * 32 + ni * 16 + lm;
        float v = 0.25f * acc[ni][reg];
        __bf16 hh = (__bf16)v;
        Oh[(size_t)gr * 256 + gc] = hh;
        Ol[(size_t)gr * 256 + gc] = (__bf16)(v - (float)hh);
    }
}

// ---------------- attn3 flash, swapped QK^T, P fully in-register (no LDS) ----------------
__global__ __launch_bounds__(256) void k_attn3(const __bf16* __restrict__ ql,
        const __bf16* __restrict__ kk, const __bf16* __restrict__ vt,
        float* __restrict__ O_s, float* __restrict__ l_s) {
    int tid = threadIdx.x;
    int wave = tid >> 6, l = tid & 63, lm = l & 15, lq = l >> 4;
    int s = blockIdx.x, bh = blockIdx.y;
    const __bf16* qb = ql + (size_t)bh * 16384;
    bf16x8 qa[4][2];
    #pragma unroll
    for (int mi = 0; mi < 4; ++mi)
        #pragma unroll
        for (int ko = 0; ko < 2; ++ko)
            qa[mi][ko] = *(const bf16x8*)&qb[(size_t)(wave * 64 + mi * 16 + lm) * 64 + ko * 32 + lq * 8];
    f32x4 O[4][4] = {};
    float lsum[4] = {};
    for (int it = 0; it < 8; ++it) {
        int c0 = s * 512 + it * 64;
        bf16x8 kf[4][2];
        #pragma unroll
        for (int ci = 0; ci < 4; ++ci)
            #pragma unroll
            for (int ko = 0; ko < 2; ++ko)
                kf[ci][ko] = *(const bf16x8*)&kk[((size_t)bh * 8192 + c0 + ci * 16 + lm) * 64 + ko * 32 + lq * 8];
        f32x4 St[4][4] = {};
        #pragma unroll
        for (int ci = 0; ci < 4; ++ci)
            #pragma unroll
            for (int ko = 0; ko < 2; ++ko)
                #pragma unroll
                for (int mi = 0; mi < 4; ++mi)
                    St[mi][ci] = mfma_bf16(kf[ci][ko], qa[mi][ko], St[mi][ci]);
        bf16x4 pk[4][4];
        #pragma unroll
        for (int mi = 0; mi < 4; ++mi)
            #pragma unroll
            for (int ci = 0; ci < 4; ++ci)
                #pragma unroll
                for (int reg = 0; reg < 4; ++reg) {
                    float e = __expf(St[mi][ci][reg]);
                    lsum[mi] += e;
                    pk[mi][ci][reg] = (__bf16)e;
                }
        #pragma unroll
        for (int ko = 0; ko < 2; ++ko) {
            bf16x8 af[4];
            #pragma unroll
            for (int mi = 0; mi < 4; ++mi)
                #pragma unroll
                for (int r = 0; r < 4; ++r) {
                    af[mi][r]     = pk[mi][2 * ko][r];
                    af[mi][4 + r] = pk[mi][2 * ko + 1][r];
                }
            #pragma unroll
            for (int ni = 0; ni < 4; ++ni) {
                const __bf16* vrow = &vt[((size_t)bh * 64 + ni * 16 + lm) * 8192 + c0 + ko * 32 + lq * 4];
                bf16x4 v0 = *(const bf16x4*)&vrow[0];
                bf16x4 v1 = *(const bf16x4*)&vrow[16];
                bf16x8 vb;
                #pragma unroll
                for (int r = 0; r < 4; ++r) { vb[r] = v0[r]; vb[4 + r] = v1[r]; }
                #pragma unroll
                for (int mi = 0; mi < 4; ++mi)
                    O[mi][ni] = mfma_bf16(af[mi], vb, O[mi][ni]);
            }
        }
    }
    #pragma unroll
    for (int mi = 0; mi < 4; ++mi) {
        float v = lsum[mi];
        v += __shfl_xor(v, 16);
        v += __shfl_xor(v, 32);
        lsum[mi] = v;
    }
    int base = (bh * 16 + s) * 256;
    #pragma unroll
    for (int mi = 0; mi < 4; ++mi)
        if (lq == 0) l_s[base + wave * 64 + mi * 16 + lm] = lsum[mi];
    #pragma unroll
    for (int mi = 0; mi < 4; ++mi)
        #pragma unroll
        for (int reg = 0; reg < 4; ++reg) {
            int r = wave * 64 + mi * 16 + lq * 4 + reg;
            #pragma unroll
            for (int ni = 0; ni < 4; ++ni)
                O_s[((size_t)(base + r)) * 64 + ni * 16 + lm] = O[mi][ni][reg];
        }
}

// ---------------- combine attn3 splits -> t2^T hi/lo planes ----------------
__global__ __launch_bounds__(256) void k_t2combine(const float* __restrict__ O_s,
        const float* __restrict__ l_s, __bf16* __restrict__ t2th,
        __bf16* __restrict__ t2tl) {
    int idx = blockIdx.x * 256 + threadIdx.x;  // 524288
    int bh = idx >> 14, r = (idx >> 6) & 255, d = idx & 63;
    float den = 0.f, num = 0.f;
    #pragma unroll
    for (int s = 0; s < 16; ++s) {
        int b2 = (bh * 16 + s) * 256 + r;
        den += l_s[b2];
        num += O_s[(size_t)b2 * 64 + d];
    }
    float v = num / den;
    __bf16 hh = (__bf16)v;
    size_t di = ((size_t)bh * 64 + d) * 256 + r;   // transposed: [bh][d][r]
    t2th[di] = hh;
    t2tl[di] = (__bf16)(v - (float)hh);
}

// ---------------- depthwise residual conv over n: convb(bh,n,d) = conv(vt) ----------------
__global__ __launch_bounds__(256) void k_conv(const __bf16* __restrict__ vt,
        const float* __restrict__ resk, __bf16* __restrict__ convb) {
    int bh = blockIdx.y, h = bh & 7;
    int d = threadIdx.x & 63, tg = threadIdx.x >> 6;
    int t0 = blockIdx.x * 64 + tg * 16;
    __shared__ float kfs[33];
    if (threadIdx.x < 33) kfs[threadIdx.x] = resk[h * 33 + threadIdx.x];
    __syncthreads();
    const __bf16* row = vt + ((size_t)bh * 64 + d) * 8192;
    float win[48];
    #pragma unroll
    for (int c = 0; c < 6; ++c) {
        int tok0 = t0 - 16 + c * 8;
        if (tok0 >= 0 && tok0 + 7 < 8192) {
            bf16x8 v8 = *(const bf16x8*)&row[tok0];
            #pragma unroll
            for (int e = 0; e < 8; ++e) win[c * 8 + e] = (float)v8[e];
        } else {
            #pragma unroll
            for (int e = 0; e < 8; ++e) {
                int tok = tok0 + e;
                win[c * 8 + e] = (tok >= 0 && tok < 8192) ? (float)row[tok] : 0.f;
            }
        }
    }
    float o[16];
    #pragma unroll
    for (int i = 0; i < 16; ++i) o[i] = 0.f;
    #pragma unroll
    for (int j = 0; j < 33; ++j) {
        float kf = kfs[j];
        #pragma unroll
        for (int i = 0; i < 16; ++i) o[i] += kf * win[i + j];
    }
    __bf16* outr = convb + ((size_t)bh * 8192) * 64 + d;
    #pragma unroll
    for (int i = 0; i < 16; ++i)
        outr[(size_t)(t0 + i) * 64] = (__bf16)o[i];
}

// ---------------- attn1 fused: softmax(q k_l^T) @ zt2 + convb ----------------
// Chunk-pipelined: per cb (4 score cols), {kf loads -> MFMA -> exp -> z loads ->
// PV MFMA} with unnormalized accumulation; single 1/rowsum at the end. Zero LDS.
__global__ __launch_bounds__(256) void k_attn1(const __bf16* __restrict__ q,
        const __bf16* __restrict__ kl, const __bf16* __restrict__ zt2p,
        const __bf16* __restrict__ convb, __bf16* __restrict__ outp) {
    int tid = threadIdx.x;
    int wave = tid >> 6, l = tid & 63, lm = l & 15, lq = l >> 4;
    int bh = blockIdx.y;
    int t0 = blockIdx.x * 64;
    int b = bh >> 3, h = bh & 7;
    const __bf16* qb = q + (size_t)bh * 8192 * 64;
    const __bf16* kb = kl + (size_t)bh * 16384;
    const __bf16* zb = zt2p + (size_t)bh * 16384;
    int rowb = t0 + wave * 16;
    bf16x8 qa[2];
    #pragma unroll
    for (int ko = 0; ko < 2; ++ko)
        qa[ko] = *(const bf16x8*)&qb[(size_t)(rowb + lm) * 64 + ko * 32 + lq * 8];
    float cv[4][4];
    #pragma unroll
    for (int ni = 0; ni < 4; ++ni)
        #pragma unroll
        for (int reg = 0; reg < 4; ++reg)
            cv[ni][reg] = (float)convb[((size_t)bh * 8192 + rowb + lq * 4 + reg) * 64 + ni * 16 + lm];
    f32x4 O[4] = {};
    float rs = 0.f;
    #pragma unroll
    for (int cb = 0; cb < 4; ++cb) {
        bf16x8 kf[4][2];
        #pragma unroll
        for (int ci = 0; ci < 4; ++ci)
            #pragma unroll
            for (int ko = 0; ko < 2; ++ko)
                kf[ci][ko] = *(const bf16x8*)&kb[(size_t)((cb * 4 + ci) * 16 + lm) * 64 + ko * 32 + lq * 8];
        f32x4 St[4] = {};
        #pragma unroll
        for (int ci = 0; ci < 4; ++ci)
            #pragma unroll
            for (int ko = 0; ko < 2; ++ko)
                St[ci] = mfma_bf16(kf[ci][ko], qa[ko], St[ci]);
        bf16x4 pk[4];
        #pragma unroll
        for (int ci = 0; ci < 4; ++ci)
            #pragma unroll
            for (int reg = 0; reg < 4; ++reg) {
                float e = __expf(St[ci][reg]);
                rs += e;
                pk[ci][reg] = (__bf16)e;
            }
        #pragma unroll
        for (int k2 = 0; k2 < 2; ++k2) {
            int ko = cb * 2 + k2;
            bf16x8 af;
            #pragma unroll
            for (int r = 0; r < 4; ++r) {
                af[r]     = pk[2 * k2][r];
                af[4 + r] = pk[2 * k2 + 1][r];
            }
            #pragma unroll
            for (int ni = 0; ni < 4; ++ni) {
                bf16x8 zfr = *(const bf16x8*)&zb[(size_t)(ni * 16 + lm) * 256 + ko * 32 + lq * 8];
                O[ni] = mfma_bf16(af, zfr, O[ni]);
            }
        }
    }
    rs += __shfl_xor(rs, 16);
    rs += __shfl_xor(rs, 32);
    float inv = 1.f / rs;
    #pragma unroll
    for (int ni = 0; ni < 4; ++ni)
        #pragma unroll
        for (int reg = 0; reg < 4; ++reg) {
            int tok = rowb + lq * 4 + reg;
            int d = ni * 16 + lm;
            float val = O[ni][reg] * inv + cv[ni][reg];
            outp[((size_t)(b * 8192 + tok)) * 512 + h * 64 + d] = (__bf16)val;
        }
}

// ---------------- launcher ----------------
extern "C" void kernel_launch(void* const* d_in, const int* in_sizes, int n_in,
                              void* d_out, int out_size, void* d_ws, size_t ws_size,
                              hipStream_t stream) {
    const float* x    = (const float*)d_in[0];
    const float* wqkv = (const float*)d_in[1];
    const float* wout = (const float*)d_in[2];
    const float* bout = (const float*)d_in[3];
    const float* resk = (const float*)d_in[4];
    char* ws = (char*)d_ws;
    size_t off = 0;
    auto alloc = [&](size_t bytes) {
        char* p = ws + off;
        off += (bytes + 255) & ~(size_t)255;
        return p;
    };
    const size_t PL = 2097152;                   // elems per 4MB bf16 plane (32x256x256)
    __bf16* q_bf   = (__bf16*)alloc(33554432);   // (bh,n,d)
    __bf16* k_bf   = (__bf16*)alloc(33554432);   // (bh,n,d)
    __bf16* vt     = (__bf16*)alloc(33554432);   // (bh,d,n)
    __bf16* outpre = (__bf16*)alloc(33554432);   // v_tmp early, attn1 out later
    __bf16* q_l    = (__bf16*)alloc(1048576);
    __bf16* k_l    = (__bf16*)alloc(1048576);
    __bf16* a2h    = (__bf16*)alloc(8388608);    // attn2 hi/lo planes; An slot later
    __bf16* zAh    = (__bf16*)alloc(8388608);
    __bf16* zBh    = (__bf16*)alloc(8388608);
    __bf16* Amh    = (__bf16*)alloc(8388608);
    __bf16* W2h    = (__bf16*)alloc(8388608);
    __bf16* W3h    = (__bf16*)alloc(8388608);
    float*  O_s    = (float*)alloc(33554432);    // xb early, attn3 out, convb late
    float*  l_s    = (float*)alloc(524288);
    __bf16* t2th   = (__bf16*)alloc(2097152);    // t2^T hi/lo planes (1MB each)
    __bf16* zt2t   = (__bf16*)alloc(1048576);
    __bf16* wqkvt  = (__bf16*)alloc(1572864);
    __bf16* woutt  = (__bf16*)alloc(524288);
    float*  stats  = (float*)alloc(256);
    __bf16* convb  = (__bf16*)O_s;               // alias (32 MB <= 33.5 MB)
    __bf16* xb     = (__bf16*)O_s;               // alias: x bf16, dead before attn3
    __bf16* a2l = a2h + PL;
    __bf16* zAl = zAh + PL;
    __bf16* zBl = zBh + PL;
    __bf16* Aml = Amh + PL;
    __bf16* W2l = W2h + PL;
    __bf16* W3l = W3h + PL;
    __bf16* t2tl = t2th + 524288;

    k_init_stats<<<1, 1, 0, stream>>>(stats);
    k_cvt<<<8192, 256, 0, stream>>>(x, xb);
    k_transpose_f32<<<dim3(8, 24), 256, 0, stream>>>(wqkv, wqkvt, 512, 1536);
    k_transpose_f32<<<dim3(8, 8), 256, 0, stream>>>(wout, woutt, 512, 512);
    k_gemm_big<0><<<dim3(256, 12), 256, 0, stream>>>(xb, wqkvt, 512,
            q_bf, k_bf, outpre, nullptr, nullptr);
    k_transpose_bf<<<dim3(128, 1, 32), 256, 0, stream>>>(outpre, vt, 8192, 64, 524288, 524288);
    k_landmarks<<<4096, 256, 0, stream>>>(q_bf, k_bf, q_l, k_l);
    k_attn2<<<dim3(4, 32), 256, 0, stream>>>(q_l, k_l, a2h, a2l);
    k_stats<<<32, 256, 0, stream>>>(a2h, a2l, stats);
    k_z0<<<8192, 256, 0, stream>>>(a2h, a2l, stats, zAh, zAl);
    k_attn3<<<dim3(16, 32), 256, 0, stream>>>(q_l, k_bf, vt, O_s, l_s);
    k_t2combine<<<2048, 256, 0, stream>>>(O_s, l_s, t2th, t2tl);
    k_conv<<<dim3(128, 32), 256, 0, stream>>>(vt, resk, convb);
    // A0 = s*(attn2 @ attn2^T)  (z0^T = s*attn2, so right-operand rows = attn2 rows)
    k_pgemm<<<dim3(8, 4, 32), 256, 0, stream>>>(a2h, a2l, a2h, a2l,
            nullptr, nullptr, Amh, Aml, 1.f, stats, 0.f, 0.f, 0, 65536);
    __bf16 *zch = zAh, *zcl = zAl, *znh = zBh, *znl = zBl;
    __bf16 *Ach = Amh, *Acl = Aml, *Anh = a2h, *Anl = a2l;   // attn2 planes dead after A0
    for (int it = 0; it < 6; ++it) {
        k_pgemm<<<dim3(8, 4, 32), 256, 0, stream>>>(Ach, Acl, Ach, Acl,
                Ach, Acl, W2h, W2l, 1.f, nullptr, -7.f, 15.f, 0, 65536);  // W2 = 15I - 7A + A@A
        k_pgemm<<<dim3(8, 4, 32), 256, 0, stream>>>(Ach, Acl, W2h, W2l,
                nullptr, nullptr, W3h, W3l, -1.f, nullptr, 0.f, 13.f, 0, 65536); // W3 = 13I - A@W2
        if (it < 5) {
            k_pgemm_dual<<<dim3(8, 4, 64), 256, 0, stream>>>(zch, zcl, Ach, Acl,
                    W3h, W3l, znh, znl, Anh, Anl);
            __bf16* t;
            t = Ach; Ach = Anh; Anh = t;
            t = Acl; Acl = Anl; Anl = t;
        } else {
            k_pgemm_dual<<<dim3(8, 4, 32), 256, 0, stream>>>(zch, zcl, zch, zcl,
                    W3h, W3l, znh, znl, znh, znl);
        }
        __bf16* t;
        t = zch; zch = znh; znh = t;
        t = zcl; zcl = znl; znl = t;
    }
    // zt2t[bh][d][slot] = (z_final @ t2)^T, bf16, slot-permuted for attn1's PV
    k_pgemm<<<dim3(8, 1, 32), 256, 0, stream>>>(zch, zcl, t2th, t2tl,
            nullptr, nullptr, zt2t, nullptr, 1.f, nullptr, 0.f, 0.f, 1, 16384);
    k_attn1<<<dim3(128, 32), 256, 0, stream>>>(q_bf, k_l, zt2t, convb, outpre);
    k_gemm_big<1><<<dim3(256, 4), 256, 0, stream>>>(outpre, woutt, 512,
            nullptr, nullptr, nullptr, (float*)d_out, bout);
}

// Round 4
// 870.388 us; speedup vs baseline: 1.2880x; 1.2880x over previous
//
#include <hip/hip_runtime.h>
#include <stdint.h>
#include <stddef.h>

// RRT/Nystrom attention, MI355X gfx950.
// Inputs/outputs FLOAT32. Heavy GEMMs: bf16 MFMA + fp32 accumulate,
// staged via global_load_lds(16B) with XOR chunk-swizzle (rule #21:
// linear LDS dest + inverse-swizzled global source + swizzled read).
// Moore-Penrose chain: round-1 structure (f32 matrices, split-bf16 hi/lo
// staged through LDS per k-step) - measured best.
// Softmaxes WITHOUT max-subtraction: scores O(1) by construction.
// attn1/attn3: swapped-QK^T (mfma(K,Q)) keeps P-rows lane-local; PV A-frag
// built in-register via k-slot permutation slot(ko,lq,j) -> m =
// (2ko+(j>>2))*16+lq*4+(j&3); zt2t stored pre-permuted by its producer.
// attn1: 64 rows/wave (attn3 shape) to amortize kf/zfr loads 4x.

typedef __bf16 bf16x8 __attribute__((ext_vector_type(8)));
typedef __bf16 bf16x4 __attribute__((ext_vector_type(4)));
typedef float f32x4 __attribute__((ext_vector_type(4)));

__device__ __forceinline__ f32x4 mfma_bf16(bf16x8 a, bf16x8 b, f32x4 c) {
    return __builtin_amdgcn_mfma_f32_16x16x32_bf16(a, b, c, 0, 0, 0);
}

__device__ __forceinline__ void gload16(const __bf16* g, __bf16* l) {
    __builtin_amdgcn_global_load_lds(
        (const __attribute__((address_space(1))) void*)g,
        (__attribute__((address_space(3))) void*)l, 16, 0, 0);
}

// ---------------- init ----------------
__global__ void k_init_stats(float* stats) { stats[0] = 0.f; stats[1] = 0.f; }

// ---------------- x f32 -> bf16 ----------------
__global__ __launch_bounds__(256) void k_cvt(const float* __restrict__ in,
        __bf16* __restrict__ out) {
    size_t base = ((size_t)blockIdx.x * 256 + threadIdx.x) * 8;
    float4 a = *(const float4*)&in[base];
    float4 b = *(const float4*)&in[base + 4];
    bf16x8 o;
    o[0] = (__bf16)a.x; o[1] = (__bf16)a.y; o[2] = (__bf16)a.z; o[3] = (__bf16)a.w;
    o[4] = (__bf16)b.x; o[5] = (__bf16)b.y; o[6] = (__bf16)b.z; o[7] = (__bf16)b.w;
    *(bf16x8*)&out[base] = o;
}

// ---------------- f32 -> bf16 transposed copy (weights), 64x64 tiles ----------------
__global__ __launch_bounds__(256) void k_transpose_f32(const float* __restrict__ in,
        __bf16* __restrict__ out, int R, int C) {
    __shared__ __bf16 tile[64 * 72];
    int r0 = blockIdx.x * 64, c0 = blockIdx.y * 64;
    int tid = threadIdx.x;
    #pragma unroll
    for (int i = 0; i < 16; ++i) {
        int slot = i * 256 + tid;
        int rr = slot >> 6, cc = slot & 63;
        tile[rr * 72 + cc] = (__bf16)in[(size_t)(r0 + rr) * C + c0 + cc];
    }
    __syncthreads();
    #pragma unroll
    for (int i = 0; i < 2; ++i) {
        int slot = i * 256 + tid;
        int cc = slot >> 3, s = slot & 7;
        bf16x8 t;
        #pragma unroll
        for (int j = 0; j < 8; ++j) t[j] = tile[(s * 8 + j) * 72 + cc];
        *(bf16x8*)&out[(size_t)(c0 + cc) * R + r0 + s * 8] = t;
    }
}

// ---------------- bf16 transpose, 64x64 tiles (for v -> vt) ----------------
__global__ __launch_bounds__(256) void k_transpose_bf(const __bf16* __restrict__ in,
        __bf16* __restrict__ out, int R, int C, long bsi, long bso) {
    __shared__ __bf16 tile[64 * 72];
    in  += (size_t)blockIdx.z * bsi;
    out += (size_t)blockIdx.z * bso;
    int r0 = blockIdx.x * 64, c0 = blockIdx.y * 64;
    int tid = threadIdx.x;
    #pragma unroll
    for (int i = 0; i < 2; ++i) {
        int slot = i * 256 + tid;
        int rr = slot >> 3, s = slot & 7;
        *(bf16x8*)&tile[rr * 72 + s * 8] =
            *(const bf16x8*)&in[(size_t)(r0 + rr) * C + c0 + s * 8];
    }
    __syncthreads();
    #pragma unroll
    for (int i = 0; i < 2; ++i) {
        int slot = i * 256 + tid;
        int cc = slot >> 3, s = slot & 7;
        bf16x8 t;
        #pragma unroll
        for (int j = 0; j < 8; ++j) t[j] = tile[(s * 8 + j) * 72 + cc];
        *(bf16x8*)&out[(size_t)(c0 + cc) * R + r0 + s * 8] = t;
    }
}

// ---------------- big GEMM: C = A(MxK,bf16) @ Bt(NxK,bf16)^T ----------------
// 128x128 tile, BK=64, gload_lds staging, XOR chunk-swizzle both sides.
template<int MODE>
__global__ __launch_bounds__(256) void k_gemm_big(const __bf16* __restrict__ A,
        const __bf16* __restrict__ Bt, int K,
        __bf16* __restrict__ qp, __bf16* __restrict__ kp, __bf16* __restrict__ vp,
        float* __restrict__ outp, const float* __restrict__ bias) {
    __shared__ __bf16 sA[128 * 64];
    __shared__ __bf16 sB[128 * 64];
    int tid = threadIdx.x;
    int wave = tid >> 6, l = tid & 63, lm = l & 15, lq = l >> 4;
    int wm = wave & 1, wn = wave >> 1;
    int m0 = blockIdx.x * 128, n0 = blockIdx.y * 128;
    int lr = l >> 3, lc8 = l & 7;
    int src_c = (lc8 ^ lr) * 8;          // inverse-swizzled source column
    f32x4 acc[4][4] = {};
    for (int k0 = 0; k0 < K; k0 += 64) {
        #pragma unroll
        for (int i = 0; i < 4; ++i) {
            int g = wave * 4 + i;        // 8-row group
            gload16(&A[(size_t)(m0 + g * 8 + lr) * K + k0 + src_c], &sA[g * 512]);
        }
        #pragma unroll
        for (int i = 0; i < 4; ++i) {
            int g = wave * 4 + i;
            gload16(&Bt[(size_t)(n0 + g * 8 + lr) * K + k0 + src_c], &sB[g * 512]);
        }
        __syncthreads();
        #pragma unroll
        for (int ko = 0; ko < 2; ++ko) {
            int ch = (ko << 2) | lq;     // chunk index 0..7
            bf16x8 af[4], bfr[4];
            #pragma unroll
            for (int mi = 0; mi < 4; ++mi) {
                int r = wm * 64 + mi * 16 + lm;
                af[mi] = *(bf16x8*)&sA[r * 64 + ((ch ^ (r & 7)) << 3)];
            }
            #pragma unroll
            for (int ni = 0; ni < 4; ++ni) {
                int r = wn * 64 + ni * 16 + lm;
                bfr[ni] = *(bf16x8*)&sB[r * 64 + ((ch ^ (r & 7)) << 3)];
            }
            #pragma unroll
            for (int mi = 0; mi < 4; ++mi)
                #pragma unroll
                for (int ni = 0; ni < 4; ++ni)
                    acc[mi][ni] = mfma_bf16(af[mi], bfr[ni], acc[mi][ni]);
        }
        __syncthreads();
    }
    #pragma unroll
    for (int mi = 0; mi < 4; ++mi)
    #pragma unroll
    for (int ni = 0; ni < 4; ++ni)
    #pragma unroll
    for (int reg = 0; reg < 4; ++reg) {
        int gr = m0 + wm * 64 + mi * 16 + lq * 4 + reg;
        int gc = n0 + wn * 64 + ni * 16 + lm;
        float v = acc[mi][ni][reg];
        if (MODE == 0) {
            int which = gc >> 9, rem = gc & 511;
            int h = rem >> 6, d = rem & 63;
            int b = gr >> 13, tok = gr & 8191;
            size_t dst = ((size_t)((b * 8 + h) * 8192 + tok)) * 64 + d;
            if (which == 0)      qp[dst] = (__bf16)(v * 0.125f);
            else if (which == 1) kp[dst] = (__bf16)v;
            else                 vp[dst] = (__bf16)v;
        } else {
            outp[(size_t)gr * 512 + gc] = v + bias[gc];
        }
    }
}

// ---------------- landmark means (q_l, k_l) ----------------
__global__ __launch_bounds__(256) void k_landmarks(const __bf16* __restrict__ q,
        const __bf16* __restrict__ k, __bf16* __restrict__ ql, __bf16* __restrict__ kl) {
    int idx = blockIdx.x * 256 + threadIdx.x;
    int sel = idx >> 19;
    int rem = idx & 524287;
    int bh = rem >> 14;
    int m  = (rem >> 6) & 255;
    int d  = rem & 63;
    const __bf16* src = sel ? k : q;
    __bf16* dst = sel ? kl : ql;
    const __bf16* p = src + ((size_t)(bh * 8192 + m * 32)) * 64 + d;
    float s = 0.f;
    #pragma unroll
    for (int j = 0; j < 32; ++j) s += (float)p[j * 64];
    dst[(size_t)bh * 16384 + m * 64 + d] = (__bf16)(s * (1.f / 32.f));
}

// ---------------- attn2 = softmax(q_l @ k_l^T), fp32 out (no-max softmax) ----------------
__global__ __launch_bounds__(256) void k_attn2(const __bf16* __restrict__ ql,
        const __bf16* __restrict__ kl, float* __restrict__ attn2) {
    int tid = threadIdx.x;
    int wave = tid >> 6, l = tid & 63, lm = l & 15, lq = l >> 4;
    int bh = blockIdx.y;
    int r0 = blockIdx.x * 64 + wave * 16;
    const __bf16* qb = ql + (size_t)bh * 16384;
    const __bf16* kb = kl + (size_t)bh * 16384;
    bf16x8 af[2];
    #pragma unroll
    for (int ko = 0; ko < 2; ++ko)
        af[ko] = *(const bf16x8*)&qb[(size_t)(r0 + lm) * 64 + ko * 32 + lq * 8];
    f32x4 S[16] = {};
    #pragma unroll
    for (int ci = 0; ci < 16; ++ci)
        #pragma unroll
        for (int ko = 0; ko < 2; ++ko) {
            bf16x8 bfr = *(const bf16x8*)&kb[(size_t)(ci * 16 + lm) * 64 + ko * 32 + lq * 8];
            S[ci] = mfma_bf16(af[ko], bfr, S[ci]);
        }
    float* out = attn2 + (size_t)bh * 65536;
    #pragma unroll
    for (int reg = 0; reg < 4; ++reg) {
        float sum = 0.f;
        #pragma unroll
        for (int ci = 0; ci < 16; ++ci) {
            float e = __expf(S[ci][reg]); S[ci][reg] = e; sum += e;
        }
        #pragma unroll
        for (int msk = 1; msk < 16; msk <<= 1) sum += __shfl_xor(sum, msk);
        float inv = 1.f / sum;
        int row = r0 + lq * 4 + reg;
        #pragma unroll
        for (int ci = 0; ci < 16; ++ci)
            out[(size_t)row * 256 + ci * 16 + lm] = S[ci][reg] * inv;
    }
}

// ---------------- max row-sum / col-sum of attn2 ----------------
__global__ __launch_bounds__(256) void k_stats(const float* __restrict__ attn2, float* stats) {
    __shared__ float red[256];
    int tid = threadIdx.x;
    const float* a = attn2 + (size_t)blockIdx.x * 65536;
    float cs = 0.f, rs = 0.f;
    for (int r = 0; r < 256; ++r) cs += a[r * 256 + tid];
    for (int c = 0; c < 256; ++c) rs += a[tid * 256 + c];
    red[tid] = cs; __syncthreads();
    for (int off = 128; off > 0; off >>= 1) {
        if (tid < off) red[tid] = fmaxf(red[tid], red[tid + off]);
        __syncthreads();
    }
    if (tid == 0) atomicMax((int*)&stats[1], __float_as_int(red[0]));
    __syncthreads();
    red[tid] = rs; __syncthreads();
    for (int off = 128; off > 0; off >>= 1) {
        if (tid < off) red[tid] = fmaxf(red[tid], red[tid + off]);
        __syncthreads();
    }
    if (tid == 0) atomicMax((int*)&stats[0], __float_as_int(red[0]));
}

// ---------------- z0 = attn2^T / (max_rowsum * max_colsum) ----------------
__global__ __launch_bounds__(256) void k_z0(const float* __restrict__ attn2,
        const float* __restrict__ stats, float* __restrict__ z) {
    int idx = blockIdx.x * 256 + threadIdx.x;
    int bh = idx >> 16, r = (idx >> 8) & 255, c = idx & 255;
    float inv = 1.f / (stats[0] * stats[1]);
    z[idx] = attn2[((size_t)bh << 16) + (size_t)c * 256 + r] * inv;
}

// ---------------- split-bf16 MFMA GEMM core (64x64 tile, K=256) ----------------
__device__ __forceinline__ void pinv_core(const float* __restrict__ A,
        const float* __restrict__ B, int ldb, int m0, int n0,
        __bf16* sAh, __bf16* sAl, __bf16* sBh, __bf16* sBl, f32x4 acc[2][2]) {
    int tid = threadIdx.x;
    int wave = tid >> 6, l = tid & 63, lm = l & 15, lq = l >> 4;
    int wm = wave & 1, wn = wave >> 1;
    for (int k0 = 0; k0 < 256; k0 += 64) {
        #pragma unroll
        for (int i = 0; i < 4; ++i) {
            int slot = i * 256 + tid;
            int r = slot >> 4, kq = slot & 15;
            float4 a4 = *(const float4*)&A[(size_t)(m0 + r) * 256 + k0 + kq * 4];
            float av[4] = {a4.x, a4.y, a4.z, a4.w};
            bf16x4 h, lo;
            #pragma unroll
            for (int j = 0; j < 4; ++j) {
                __bf16 hh = (__bf16)av[j];
                h[j] = hh;
                lo[j] = (__bf16)(av[j] - (float)hh);
            }
            *(bf16x4*)&sAh[r * 72 + kq * 4] = h;
            *(bf16x4*)&sAl[r * 72 + kq * 4] = lo;
        }
        #pragma unroll
        for (int i = 0; i < 4; ++i) {
            int slot = i * 256 + tid;
            int kk = slot >> 4, c4 = (slot & 15) * 4;
            float4 b4 = *(const float4*)&B[(size_t)(k0 + kk) * ldb + n0 + c4];
            float bv[4] = {b4.x, b4.y, b4.z, b4.w};
            #pragma unroll
            for (int j = 0; j < 4; ++j) {
                __bf16 hh = (__bf16)bv[j];
                sBh[(c4 + j) * 72 + kk] = hh;
                sBl[(c4 + j) * 72 + kk] = (__bf16)(bv[j] - (float)hh);
            }
        }
        __syncthreads();
        #pragma unroll
        for (int ko = 0; ko < 2; ++ko) {
            bf16x8 ah[2], al2[2], bhf[2], blf[2];
            #pragma unroll
            for (int mi = 0; mi < 2; ++mi) {
                ah[mi]  = *(bf16x8*)&sAh[(wm * 32 + mi * 16 + lm) * 72 + ko * 32 + lq * 8];
                al2[mi] = *(bf16x8*)&sAl[(wm * 32 + mi * 16 + lm) * 72 + ko * 32 + lq * 8];
            }
            #pragma unroll
            for (int ni = 0; ni < 2; ++ni) {
                bhf[ni] = *(bf16x8*)&sBh[(wn * 32 + ni * 16 + lm) * 72 + ko * 32 + lq * 8];
                blf[ni] = *(bf16x8*)&sBl[(wn * 32 + ni * 16 + lm) * 72 + ko * 32 + lq * 8];
            }
            #pragma unroll
            for (int mi = 0; mi < 2; ++mi)
                #pragma unroll
                for (int ni = 0; ni < 2; ++ni) {
                    acc[mi][ni] = mfma_bf16(ah[mi], bhf[ni], acc[mi][ni]);
                    acc[mi][ni] = mfma_bf16(ah[mi], blf[ni], acc[mi][ni]);
                    acc[mi][ni] = mfma_bf16(al2[mi], bhf[ni], acc[mi][ni]);
                }
        }
        __syncthreads();
    }
}

// out = delta*I + alpha*(A@B) + beta*Cin ; outMode 1 -> bf16 slot-permuted zt2t
__global__ __launch_bounds__(256) void k_pinv_mfma(const float* __restrict__ A,
        const float* __restrict__ B, const float* __restrict__ Cin,
        void* __restrict__ Out, float alpha, float beta, float delta,
        int ldb, int outMode) {
    __shared__ __bf16 sAh[64 * 72], sAl[64 * 72];
    __shared__ __bf16 sBh[64 * 72], sBl[64 * 72];
    int tid = threadIdx.x;
    int wave = tid >> 6, l = tid & 63, lm = l & 15, lq = l >> 4;
    int wm = wave & 1, wn = wave >> 1;
    int bh = blockIdx.z;
    int m0 = blockIdx.x * 64, n0 = blockIdx.y * 64;
    const float* Cb = Cin ? Cin + (size_t)bh * 65536 : nullptr;
    f32x4 acc[2][2] = {};
    pinv_core(A + (size_t)bh * 65536, B + (size_t)bh * 256 * (size_t)ldb, ldb,
              m0, n0, sAh, sAl, sBh, sBl, acc);
    #pragma unroll
    for (int mi = 0; mi < 2; ++mi)
    #pragma unroll
    for (int ni = 0; ni < 2; ++ni)
    #pragma unroll
    for (int reg = 0; reg < 4; ++reg) {
        int gr = m0 + wm * 32 + mi * 16 + lq * 4 + reg;
        int gc = n0 + wn * 32 + ni * 16 + lm;
        float v = alpha * acc[mi][ni][reg];
        if (beta != 0.f) v += beta * Cb[(size_t)gr * 256 + gc];
        if (gr == gc) v += delta;
        if (outMode == 0) {
            ((float*)Out)[(size_t)bh * 65536 + (size_t)gr * 256 + gc] = v;
        } else {
            int ci2 = gr >> 4, lqm = (gr >> 2) & 3, r = gr & 3;
            int slot = ((ci2 >> 1) << 5) + (lqm << 3) + ((ci2 & 1) << 2) + r;
            ((__bf16*)Out)[(size_t)bh * 16384 + (size_t)gc * 256 + slot] = (__bf16)v;
        }
    }
}

// dual update: z' = 0.25 z@W3 (blocks z<32) and A' = 0.25 A@W3 (blocks z>=32)
__global__ __launch_bounds__(256) void k_pinv_dual(const float* __restrict__ Az,
        const float* __restrict__ Aa, const float* __restrict__ B,
        float* __restrict__ Oz, float* __restrict__ Oa) {
    __shared__ __bf16 sAh[64 * 72], sAl[64 * 72];
    __shared__ __bf16 sBh[64 * 72], sBl[64 * 72];
    int tid = threadIdx.x;
    int wave = tid >> 6, l = tid & 63, lm = l & 15, lq = l >> 4;
    int wm = wave & 1, wn = wave >> 1;
    int z = blockIdx.z, bh = z & 31;
    const float* A = (z >= 32 ? Aa : Az) + (size_t)bh * 65536;
    float* Out = (z >= 32 ? Oa : Oz) + (size_t)bh * 65536;
    int m0 = blockIdx.x * 64, n0 = blockIdx.y * 64;
    f32x4 acc[2][2] = {};
    pinv_core(A, B + (size_t)bh * 65536, 256, m0, n0, sAh, sAl, sBh, sBl, acc);
    #pragma unroll
    for (int mi = 0; mi < 2; ++mi)
    #pragma unroll
    for (int ni = 0; ni < 2; ++ni)
    #pragma unroll
    for (int reg = 0; reg < 4; ++reg) {
        int gr = m0 + wm * 32 + mi * 16 + lq * 4 + reg;
        int gc = n0 + wn * 32 + ni * 16 + lm;
        Out[(size_t)gr * 256 + gc] = 0.25f * acc[mi][ni][reg];
    }
}

// ---------------- attn3 flash, swapped QK^T, P fully in-register (no LDS) ----------------
__global__ __launch_bounds__(256) void k_attn3(const __bf16* __restrict__ ql,
        const __bf16* __restrict__ kk, const __bf16* __restrict__ vt,
        float* __restrict__ O_s, float* __restrict__ l_s) {
    int tid = threadIdx.x;
    int wave = tid >> 6, l = tid & 63, lm = l & 15, lq = l >> 4;
    int s = blockIdx.x, bh = blockIdx.y;
    const __bf16* qb = ql + (size_t)bh * 16384;
    bf16x8 qa[4][2];
    #pragma unroll
    for (int mi = 0; mi < 4; ++mi)
        #pragma unroll
        for (int ko = 0; ko < 2; ++ko)
            qa[mi][ko] = *(const bf16x8*)&qb[(size_t)(wave * 64 + mi * 16 + lm) * 64 + ko * 32 + lq * 8];
    f32x4 O[4][4] = {};
    float lsum[4] = {};
    for (int it = 0; it < 8; ++it) {
        int c0 = s * 512 + it * 64;
        bf16x8 kf[4][2];
        #pragma unroll
        for (int ci = 0; ci < 4; ++ci)
            #pragma unroll
            for (int ko = 0; ko < 2; ++ko)
                kf[ci][ko] = *(const bf16x8*)&kk[((size_t)bh * 8192 + c0 + ci * 16 + lm) * 64 + ko * 32 + lq * 8];
        f32x4 St[4][4] = {};
        #pragma unroll
        for (int ci = 0; ci < 4; ++ci)
            #pragma unroll
            for (int ko = 0; ko < 2; ++ko)
                #pragma unroll
                for (int mi = 0; mi < 4; ++mi)
                    St[mi][ci] = mfma_bf16(kf[ci][ko], qa[mi][ko], St[mi][ci]);
        bf16x4 pk[4][4];
        #pragma unroll
        for (int mi = 0; mi < 4; ++mi)
            #pragma unroll
            for (int ci = 0; ci < 4; ++ci)
                #pragma unroll
                for (int reg = 0; reg < 4; ++reg) {
                    float e = __expf(St[mi][ci][reg]);
                    lsum[mi] += e;
                    pk[mi][ci][reg] = (__bf16)e;
                }
        #pragma unroll
        for (int ko = 0; ko < 2; ++ko) {
            bf16x8 af[4];
            #pragma unroll
            for (int mi = 0; mi < 4; ++mi)
                #pragma unroll
                for (int r = 0; r < 4; ++r) {
                    af[mi][r]     = pk[mi][2 * ko][r];
                    af[mi][4 + r] = pk[mi][2 * ko + 1][r];
                }
            #pragma unroll
            for (int ni = 0; ni < 4; ++ni) {
                const __bf16* vrow = &vt[((size_t)bh * 64 + ni * 16 + lm) * 8192 + c0 + ko * 32 + lq * 4];
                bf16x4 v0 = *(const bf16x4*)&vrow[0];
                bf16x4 v1 = *(const bf16x4*)&vrow[16];
                bf16x8 vb;
                #pragma unroll
                for (int r = 0; r < 4; ++r) { vb[r] = v0[r]; vb[4 + r] = v1[r]; }
                #pragma unroll
                for (int mi = 0; mi < 4; ++mi)
                    O[mi][ni] = mfma_bf16(af[mi], vb, O[mi][ni]);
            }
        }
    }
    #pragma unroll
    for (int mi = 0; mi < 4; ++mi) {
        float v = lsum[mi];
        v += __shfl_xor(v, 16);
        v += __shfl_xor(v, 32);
        lsum[mi] = v;
    }
    int base = (bh * 16 + s) * 256;
    #pragma unroll
    for (int mi = 0; mi < 4; ++mi)
        if (lq == 0) l_s[base + wave * 64 + mi * 16 + lm] = lsum[mi];
    #pragma unroll
    for (int mi = 0; mi < 4; ++mi)
        #pragma unroll
        for (int reg = 0; reg < 4; ++reg) {
            int r = wave * 64 + mi * 16 + lq * 4 + reg;
            #pragma unroll
            for (int ni = 0; ni < 4; ++ni)
                O_s[((size_t)(base + r)) * 64 + ni * 16 + lm] = O[mi][ni][reg];
        }
}

// ---------------- combine attn3 splits (plain sums) ----------------
__global__ __launch_bounds__(256) void k_t2combine(const float* __restrict__ O_s,
        const float* __restrict__ l_s, float* __restrict__ t2) {
    int idx = blockIdx.x * 256 + threadIdx.x;  // 524288
    int bh = idx >> 14, r = (idx >> 6) & 255, d = idx & 63;
    float den = 0.f, num = 0.f;
    #pragma unroll
    for (int s = 0; s < 16; ++s) {
        int b2 = (bh * 16 + s) * 256 + r;
        den += l_s[b2];
        num += O_s[(size_t)b2 * 64 + d];
    }
    t2[((size_t)bh * 256 + r) * 64 + d] = num / den;
}

// ---------------- depthwise residual conv over n: convb(bh,n,d) = conv(vt) ----------------
__global__ __launch_bounds__(256) void k_conv(const __bf16* __restrict__ vt,
        const float* __restrict__ resk, __bf16* __restrict__ convb) {
    int bh = blockIdx.y, h = bh & 7;
    int d = threadIdx.x & 63, tg = threadIdx.x >> 6;
    int t0 = blockIdx.x * 64 + tg * 16;
    __shared__ float kfs[33];
    if (threadIdx.x < 33) kfs[threadIdx.x] = resk[h * 33 + threadIdx.x];
    __syncthreads();
    const __bf16* row = vt + ((size_t)bh * 64 + d) * 8192;
    float win[48];
    #pragma unroll
    for (int c = 0; c < 6; ++c) {
        int tok0 = t0 - 16 + c * 8;
        if (tok0 >= 0 && tok0 + 7 < 8192) {
            bf16x8 v8 = *(const bf16x8*)&row[tok0];
            #pragma unroll
            for (int e = 0; e < 8; ++e) win[c * 8 + e] = (float)v8[e];
        } else {
            #pragma unroll
            for (int e = 0; e < 8; ++e) {
                int tok = tok0 + e;
                win[c * 8 + e] = (tok >= 0 && tok < 8192) ? (float)row[tok] : 0.f;
            }
        }
    }
    float o[16];
    #pragma unroll
    for (int i = 0; i < 16; ++i) o[i] = 0.f;
    #pragma unroll
    for (int j = 0; j < 33; ++j) {
        float kf = kfs[j];
        #pragma unroll
        for (int i = 0; i < 16; ++i) o[i] += kf * win[i + j];
    }
    __bf16* outr = convb + ((size_t)bh * 8192) * 64 + d;
    #pragma unroll
    for (int i = 0; i < 16; ++i)
        outr[(size_t)(t0 + i) * 64] = (__bf16)o[i];
}

// ---------------- attn1 fused: softmax(q k_l^T) @ zt2 + convb ----------------
// 64 rows/wave (attn3 shape): kf/zfr loads amortized over 4 mi sub-tiles.
// Unnormalized accumulation; exact per-row 1/rowsum fetched via shfl. Zero LDS.
__global__ __launch_bounds__(256) void k_attn1(const __bf16* __restrict__ q,
        const __bf16* __restrict__ kl, const __bf16* __restrict__ zt2p,
        const __bf16* __restrict__ convb, __bf16* __restrict__ outp) {
    int tid = threadIdx.x;
    int wave = tid >> 6, l = tid & 63, lm = l & 15, lq = l >> 4;
    int bh = blockIdx.y;
    int t0 = blockIdx.x * 256;
    int b = bh >> 3, h = bh & 7;
    const __bf16* qb = q + (size_t)bh * 8192 * 64;
    const __bf16* kb = kl + (size_t)bh * 16384;
    const __bf16* zb = zt2p + (size_t)bh * 16384;
    int rowb = t0 + wave * 64;
    // b-frag: Q[col=lm -> row rowb+mi*16+lm][d]
    bf16x8 qa[4][2];
    #pragma unroll
    for (int mi = 0; mi < 4; ++mi)
        #pragma unroll
        for (int ko = 0; ko < 2; ++ko)
            qa[mi][ko] = *(const bf16x8*)&qb[(size_t)(rowb + mi * 16 + lm) * 64 + ko * 32 + lq * 8];
    f32x4 O[4][4] = {};
    float rs[4] = {};
    #pragma unroll
    for (int c2 = 0; c2 < 8; ++c2) {       // 2 landmark-cols blocks per chunk
        bf16x8 kf[2][2];
        #pragma unroll
        for (int ci = 0; ci < 2; ++ci)
            #pragma unroll
            for (int ko = 0; ko < 2; ++ko)
                kf[ci][ko] = *(const bf16x8*)&kb[(size_t)((c2 * 2 + ci) * 16 + lm) * 64 + ko * 32 + lq * 8];
        f32x4 St[4][2] = {};
        #pragma unroll
        for (int ci = 0; ci < 2; ++ci)
            #pragma unroll
            for (int ko = 0; ko < 2; ++ko)
                #pragma unroll
                for (int mi = 0; mi < 4; ++mi)
                    St[mi][ci] = mfma_bf16(kf[ci][ko], qa[mi][ko], St[mi][ci]);
        bf16x4 pk[4][2];
        #pragma unroll
        for (int mi = 0; mi < 4; ++mi)
            #pragma unroll
            for (int ci = 0; ci < 2; ++ci)
                #pragma unroll
                for (int reg = 0; reg < 4; ++reg) {
                    float e = __expf(St[mi][ci][reg]);
                    rs[mi] += e;
                    pk[mi][ci][reg] = (__bf16)e;
                }
        // PV for k-slot group ko=c2: slot (c2,lq,j) carries m=(2c2+(j>>2))*16+lq*4+(j&3)
        bf16x8 zfr[4];
        #pragma unroll
        for (int ni = 0; ni < 4; ++ni)
            zfr[ni] = *(const bf16x8*)&zb[(size_t)(ni * 16 + lm) * 256 + c2 * 32 + lq * 8];
        #pragma unroll
        for (int mi = 0; mi < 4; ++mi) {
            bf16x8 af;
            #pragma unroll
            for (int r = 0; r < 4; ++r) {
                af[r]     = pk[mi][0][r];
                af[4 + r] = pk[mi][1][r];
            }
            #pragma unroll
            for (int ni = 0; ni < 4; ++ni)
                O[mi][ni] = mfma_bf16(af, zfr[ni], O[mi][ni]);
        }
    }
    // epilogue per mi: exact per-output-row rowsum via shfl, + conv, store
    #pragma unroll
    for (int mi = 0; mi < 4; ++mi) {
        float v = rs[mi];
        v += __shfl_xor(v, 16);
        v += __shfl_xor(v, 32);            // rowsum(rowb+mi*16+lm) on all lq-copies
        float invr[4];
        #pragma unroll
        for (int reg = 0; reg < 4; ++reg)
            invr[reg] = 1.f / __shfl(v, lq * 4 + reg);
        #pragma unroll
        for (int ni = 0; ni < 4; ++ni)
            #pragma unroll
            for (int reg = 0; reg < 4; ++reg) {
                int tok = rowb + mi * 16 + lq * 4 + reg;
                int d = ni * 16 + lm;
                float conv = (float)convb[((size_t)bh * 8192 + tok) * 64 + d];
                float val = O[mi][ni][reg] * invr[reg] + conv;
                outp[((size_t)(b * 8192 + tok)) * 512 + h * 64 + d] = (__bf16)val;
            }
    }
}

// ---------------- launcher ----------------
extern "C" void kernel_launch(void* const* d_in, const int* in_sizes, int n_in,
                              void* d_out, int out_size, void* d_ws, size_t ws_size,
                              hipStream_t stream) {
    const float* x    = (const float*)d_in[0];
    const float* wqkv = (const float*)d_in[1];
    const float* wout = (const float*)d_in[2];
    const float* bout = (const float*)d_in[3];
    const float* resk = (const float*)d_in[4];
    char* ws = (char*)d_ws;
    size_t off = 0;
    auto alloc = [&](size_t bytes) {
        char* p = ws + off;
        off += (bytes + 255) & ~(size_t)255;
        return p;
    };
    __bf16* q_bf   = (__bf16*)alloc(33554432);   // (bh,n,d)
    __bf16* k_bf   = (__bf16*)alloc(33554432);   // (bh,n,d)
    __bf16* vt     = (__bf16*)alloc(33554432);   // (bh,d,n)
    __bf16* outpre = (__bf16*)alloc(33554432);   // v_tmp early, attn1 out later
    __bf16* q_l    = (__bf16*)alloc(1048576);
    __bf16* k_l    = (__bf16*)alloc(1048576);
    float*  attn2  = (float*)alloc(8388608);     // reused as A-double-buffer after A0
    float*  zA     = (float*)alloc(8388608);
    float*  zB     = (float*)alloc(8388608);
    float*  Amat   = (float*)alloc(8388608);
    float*  W2     = (float*)alloc(8388608);
    float*  W3     = (float*)alloc(8388608);
    float*  O_s    = (float*)alloc(33554432);    // xb early, attn3 out, convb late
    float*  l_s    = (float*)alloc(524288);
    float*  t2     = (float*)alloc(2097152);
    __bf16* zt2t   = (__bf16*)alloc(1048576);
    __bf16* wqkvt  = (__bf16*)alloc(1572864);
    __bf16* woutt  = (__bf16*)alloc(524288);
    float*  stats  = (float*)alloc(256);
    __bf16* convb  = (__bf16*)O_s;               // alias (32 MB <= 33.5 MB)
    __bf16* xb     = (__bf16*)O_s;               // alias: x bf16, dead before attn3

    k_init_stats<<<1, 1, 0, stream>>>(stats);
    k_cvt<<<8192, 256, 0, stream>>>(x, xb);
    k_transpose_f32<<<dim3(8, 24), 256, 0, stream>>>(wqkv, wqkvt, 512, 1536);
    k_transpose_f32<<<dim3(8, 8), 256, 0, stream>>>(wout, woutt, 512, 512);
    k_gemm_big<0><<<dim3(256, 12), 256, 0, stream>>>(xb, wqkvt, 512,
            q_bf, k_bf, outpre, nullptr, nullptr);
    k_transpose_bf<<<dim3(128, 1, 32), 256, 0, stream>>>(outpre, vt, 8192, 64, 524288, 524288);
    k_landmarks<<<4096, 256, 0, stream>>>(q_bf, k_bf, q_l, k_l);
    k_attn2<<<dim3(4, 32), 256, 0, stream>>>(q_l, k_l, attn2);
    k_stats<<<32, 256, 0, stream>>>(attn2, stats);
    k_z0<<<8192, 256, 0, stream>>>(attn2, stats, zA);
    k_attn3<<<dim3(16, 32), 256, 0, stream>>>(q_l, k_bf, vt, O_s, l_s);
    k_t2combine<<<2048, 256, 0, stream>>>(O_s, l_s, t2);
    k_conv<<<dim3(128, 32), 256, 0, stream>>>(vt, resk, convb);
    // A0 = attn2 @ z0
    k_pinv_mfma<<<dim3(4, 4, 32), 256, 0, stream>>>(attn2, zA, nullptr, Amat,
            1.f, 0.f, 0.f, 256, 0);
    float* zc = zA;
    float* zn = zB;
    float* Ac = Amat;
    float* An = attn2;
    for (int it = 0; it < 6; ++it) {
        k_pinv_mfma<<<dim3(4, 4, 32), 256, 0, stream>>>(Ac, Ac, Ac, W2,
                1.f, -7.f, 15.f, 256, 0);                 // W2 = 15I - 7A + A@A
        k_pinv_mfma<<<dim3(4, 4, 32), 256, 0, stream>>>(Ac, W2, nullptr, W3,
                -1.f, 0.f, 13.f, 256, 0);                 // W3 = 13I - A@W2
        if (it < 5) {
            k_pinv_dual<<<dim3(4, 4, 64), 256, 0, stream>>>(zc, Ac, W3, zn, An);
            float* t = Ac; Ac = An; An = t;
        } else {
            k_pinv_dual<<<dim3(4, 4, 32), 256, 0, stream>>>(zc, zc, W3, zn, zn);
        }
        float* t = zc; zc = zn; zn = t;
    }
    // zt2t[bh][d][slot] = (z_final @ t2)^T, bf16, slot-permuted for attn1's PV
    k_pinv_mfma<<<dim3(4, 1, 32), 256, 0, stream>>>(zc, t2, nullptr, zt2t,
            1.f, 0.f, 0.f, 64, 1);
    k_attn1<<<dim3(32, 32), 256, 0, stream>>>(q_bf, k_l, zt2t, convb, outpre);
    k_gemm_big<1><<<dim3(256, 4), 256, 0, stream>>>(outpre, woutt, 512,
            nullptr, nullptr, nullptr, (float*)d_out, bout);
}

// Round 5
// 696.054 us; speedup vs baseline: 1.6106x; 1.2505x over previous
//
#include <hip/hip_runtime.h>
#include <stdint.h>
#include <stddef.h>

// RRT/Nystrom attention, MI355X gfx950.
// Inputs/outputs FLOAT32. Heavy GEMMs: bf16 MFMA + fp32 accumulate,
// staged via global_load_lds(16B) with XOR chunk-swizzle (rule #21:
// linear LDS dest + inverse-swizzled global source + swizzled read).
// Moore-Penrose chain: hi/lo bf16 planes split ONCE by each producer
// (fp32-grade via 3-plane MFMA). All chain matrices are symmetric
// (polynomials of A0 = s*attn2@attn2^T), so the MFMA B-operand's
// "B^T rows" are just rows of the same plane -> no transpose anywhere.
// pgemm stages planes through LDS with the same swizzled gload_lds as
// the big GEMM: zero convert-VALU, zero scalar ds-writes in the K-loop.
// Softmaxes WITHOUT max-subtraction: scores O(1) by construction.
// attn1/attn3: swapped-QK^T (mfma(K,Q)) keeps P-rows lane-local; PV A-frag
// built in-register via k-slot permutation slot(ko,lq,j) -> m =
// (2ko+(j>>2))*16+lq*4+(j&3); zt2t stored pre-permuted by its producer.
// attn1: 64 rows/wave to amortize kf/zfr loads 4x.

typedef __bf16 bf16x8 __attribute__((ext_vector_type(8)));
typedef __bf16 bf16x4 __attribute__((ext_vector_type(4)));
typedef float f32x4 __attribute__((ext_vector_type(4)));

__device__ __forceinline__ f32x4 mfma_bf16(bf16x8 a, bf16x8 b, f32x4 c) {
    return __builtin_amdgcn_mfma_f32_16x16x32_bf16(a, b, c, 0, 0, 0);
}

__device__ __forceinline__ void gload16(const __bf16* g, __bf16* l) {
    __builtin_amdgcn_global_load_lds(
        (const __attribute__((address_space(1))) void*)g,
        (__attribute__((address_space(3))) void*)l, 16, 0, 0);
}

// ---------------- init ----------------
__global__ void k_init_stats(float* stats) { stats[0] = 1.f; stats[1] = 0.f; }

// ---------------- x f32 -> bf16 ----------------
__global__ __launch_bounds__(256) void k_cvt(const float* __restrict__ in,
        __bf16* __restrict__ out) {
    size_t base = ((size_t)blockIdx.x * 256 + threadIdx.x) * 8;
    float4 a = *(const float4*)&in[base];
    float4 b = *(const float4*)&in[base + 4];
    bf16x8 o;
    o[0] = (__bf16)a.x; o[1] = (__bf16)a.y; o[2] = (__bf16)a.z; o[3] = (__bf16)a.w;
    o[4] = (__bf16)b.x; o[5] = (__bf16)b.y; o[6] = (__bf16)b.z; o[7] = (__bf16)b.w;
    *(bf16x8*)&out[base] = o;
}

// ---------------- f32 -> bf16 transposed copy (weights), 64x64 tiles ----------------
__global__ __launch_bounds__(256) void k_transpose_f32(const float* __restrict__ in,
        __bf16* __restrict__ out, int R, int C) {
    __shared__ __bf16 tile[64 * 72];
    int r0 = blockIdx.x * 64, c0 = blockIdx.y * 64;
    int tid = threadIdx.x;
    #pragma unroll
    for (int i = 0; i < 16; ++i) {
        int slot = i * 256 + tid;
        int rr = slot >> 6, cc = slot & 63;
        tile[rr * 72 + cc] = (__bf16)in[(size_t)(r0 + rr) * C + c0 + cc];
    }
    __syncthreads();
    #pragma unroll
    for (int i = 0; i < 2; ++i) {
        int slot = i * 256 + tid;
        int cc = slot >> 3, s = slot & 7;
        bf16x8 t;
        #pragma unroll
        for (int j = 0; j < 8; ++j) t[j] = tile[(s * 8 + j) * 72 + cc];
        *(bf16x8*)&out[(size_t)(c0 + cc) * R + r0 + s * 8] = t;
    }
}

// ---------------- bf16 transpose, 64x64 tiles (for v -> vt) ----------------
__global__ __launch_bounds__(256) void k_transpose_bf(const __bf16* __restrict__ in,
        __bf16* __restrict__ out, int R, int C, long bsi, long bso) {
    __shared__ __bf16 tile[64 * 72];
    in  += (size_t)blockIdx.z * bsi;
    out += (size_t)blockIdx.z * bso;
    int r0 = blockIdx.x * 64, c0 = blockIdx.y * 64;
    int tid = threadIdx.x;
    #pragma unroll
    for (int i = 0; i < 2; ++i) {
        int slot = i * 256 + tid;
        int rr = slot >> 3, s = slot & 7;
        *(bf16x8*)&tile[rr * 72 + s * 8] =
            *(const bf16x8*)&in[(size_t)(r0 + rr) * C + c0 + s * 8];
    }
    __syncthreads();
    #pragma unroll
    for (int i = 0; i < 2; ++i) {
        int slot = i * 256 + tid;
        int cc = slot >> 3, s = slot & 7;
        bf16x8 t;
        #pragma unroll
        for (int j = 0; j < 8; ++j) t[j] = tile[(s * 8 + j) * 72 + cc];
        *(bf16x8*)&out[(size_t)(c0 + cc) * R + r0 + s * 8] = t;
    }
}

// ---------------- big GEMM: C = A(MxK,bf16) @ Bt(NxK,bf16)^T ----------------
// 128x128 tile, BK=64, gload_lds staging, XOR chunk-swizzle both sides.
template<int MODE>
__global__ __launch_bounds__(256) void k_gemm_big(const __bf16* __restrict__ A,
        const __bf16* __restrict__ Bt, int K,
        __bf16* __restrict__ qp, __bf16* __restrict__ kp, __bf16* __restrict__ vp,
        float* __restrict__ outp, const float* __restrict__ bias) {
    __shared__ __bf16 sA[128 * 64];
    __shared__ __bf16 sB[128 * 64];
    int tid = threadIdx.x;
    int wave = tid >> 6, l = tid & 63, lm = l & 15, lq = l >> 4;
    int wm = wave & 1, wn = wave >> 1;
    int m0 = blockIdx.x * 128, n0 = blockIdx.y * 128;
    int lr = l >> 3, lc8 = l & 7;
    int src_c = (lc8 ^ lr) * 8;          // inverse-swizzled source column
    f32x4 acc[4][4] = {};
    for (int k0 = 0; k0 < K; k0 += 64) {
        #pragma unroll
        for (int i = 0; i < 4; ++i) {
            int g = wave * 4 + i;        // 8-row group
            gload16(&A[(size_t)(m0 + g * 8 + lr) * K + k0 + src_c], &sA[g * 512]);
        }
        #pragma unroll
        for (int i = 0; i < 4; ++i) {
            int g = wave * 4 + i;
            gload16(&Bt[(size_t)(n0 + g * 8 + lr) * K + k0 + src_c], &sB[g * 512]);
        }
        __syncthreads();
        #pragma unroll
        for (int ko = 0; ko < 2; ++ko) {
            int ch = (ko << 2) | lq;     // chunk index 0..7
            bf16x8 af[4], bfr[4];
            #pragma unroll
            for (int mi = 0; mi < 4; ++mi) {
                int r = wm * 64 + mi * 16 + lm;
                af[mi] = *(bf16x8*)&sA[r * 64 + ((ch ^ (r & 7)) << 3)];
            }
            #pragma unroll
            for (int ni = 0; ni < 4; ++ni) {
                int r = wn * 64 + ni * 16 + lm;
                bfr[ni] = *(bf16x8*)&sB[r * 64 + ((ch ^ (r & 7)) << 3)];
            }
            #pragma unroll
            for (int mi = 0; mi < 4; ++mi)
                #pragma unroll
                for (int ni = 0; ni < 4; ++ni)
                    acc[mi][ni] = mfma_bf16(af[mi], bfr[ni], acc[mi][ni]);
        }
        __syncthreads();
    }
    #pragma unroll
    for (int mi = 0; mi < 4; ++mi)
    #pragma unroll
    for (int ni = 0; ni < 4; ++ni)
    #pragma unroll
    for (int reg = 0; reg < 4; ++reg) {
        int gr = m0 + wm * 64 + mi * 16 + lq * 4 + reg;
        int gc = n0 + wn * 64 + ni * 16 + lm;
        float v = acc[mi][ni][reg];
        if (MODE == 0) {
            int which = gc >> 9, rem = gc & 511;
            int h = rem >> 6, d = rem & 63;
            int b = gr >> 13, tok = gr & 8191;
            size_t dst = ((size_t)((b * 8 + h) * 8192 + tok)) * 64 + d;
            if (which == 0)      qp[dst] = (__bf16)(v * 0.125f);
            else if (which == 1) kp[dst] = (__bf16)v;
            else                 vp[dst] = (__bf16)v;
        } else {
            outp[(size_t)gr * 512 + gc] = v + bias[gc];
        }
    }
}

// ---------------- landmark means (q_l, k_l) ----------------
__global__ __launch_bounds__(256) void k_landmarks(const __bf16* __restrict__ q,
        const __bf16* __restrict__ k, __bf16* __restrict__ ql, __bf16* __restrict__ kl) {
    int idx = blockIdx.x * 256 + threadIdx.x;
    int sel = idx >> 19;
    int rem = idx & 524287;
    int bh = rem >> 14;
    int m  = (rem >> 6) & 255;
    int d  = rem & 63;
    const __bf16* src = sel ? k : q;
    __bf16* dst = sel ? kl : ql;
    const __bf16* p = src + ((size_t)(bh * 8192 + m * 32)) * 64 + d;
    float s = 0.f;
    #pragma unroll
    for (int j = 0; j < 32; ++j) s += (float)p[j * 64];
    dst[(size_t)bh * 16384 + m * 64 + d] = (__bf16)(s * (1.f / 32.f));
}

// ---------------- attn2 = softmax(q_l @ k_l^T), hi/lo bf16 planes ----------------
__global__ __launch_bounds__(256) void k_attn2(const __bf16* __restrict__ ql,
        const __bf16* __restrict__ kl, __bf16* __restrict__ ph, __bf16* __restrict__ pl) {
    int tid = threadIdx.x;
    int wave = tid >> 6, l = tid & 63, lm = l & 15, lq = l >> 4;
    int bh = blockIdx.y;
    int r0 = blockIdx.x * 64 + wave * 16;
    const __bf16* qb = ql + (size_t)bh * 16384;
    const __bf16* kb = kl + (size_t)bh * 16384;
    bf16x8 af[2];
    #pragma unroll
    for (int ko = 0; ko < 2; ++ko)
        af[ko] = *(const bf16x8*)&qb[(size_t)(r0 + lm) * 64 + ko * 32 + lq * 8];
    f32x4 S[16] = {};
    #pragma unroll
    for (int ci = 0; ci < 16; ++ci)
        #pragma unroll
        for (int ko = 0; ko < 2; ++ko) {
            bf16x8 bfr = *(const bf16x8*)&kb[(size_t)(ci * 16 + lm) * 64 + ko * 32 + lq * 8];
            S[ci] = mfma_bf16(af[ko], bfr, S[ci]);
        }
    __bf16* oh = ph + (size_t)bh * 65536;
    __bf16* ol = pl + (size_t)bh * 65536;
    #pragma unroll
    for (int reg = 0; reg < 4; ++reg) {
        float sum = 0.f;
        #pragma unroll
        for (int ci = 0; ci < 16; ++ci) {
            float e = __expf(S[ci][reg]); S[ci][reg] = e; sum += e;
        }
        #pragma unroll
        for (int msk = 1; msk < 16; msk <<= 1) sum += __shfl_xor(sum, msk);
        float inv = 1.f / sum;
        int row = r0 + lq * 4 + reg;
        #pragma unroll
        for (int ci = 0; ci < 16; ++ci) {
            float v = S[ci][reg] * inv;
            __bf16 hh = (__bf16)v;
            oh[(size_t)row * 256 + ci * 16 + lm] = hh;
            ol[(size_t)row * 256 + ci * 16 + lm] = (__bf16)(v - (float)hh);
        }
    }
}

// ---------------- max col-sum of attn2 (row-sums are exactly 1) ----------------
__global__ __launch_bounds__(256) void k_stats(const __bf16* __restrict__ ph,
        const __bf16* __restrict__ pl, float* stats) {
    __shared__ float red[256];
    int tid = threadIdx.x;
    const __bf16* a = ph + (size_t)blockIdx.x * 65536;
    const __bf16* b = pl + (size_t)blockIdx.x * 65536;
    float cs = 0.f;
    for (int r = 0; r < 256; ++r)
        cs += (float)a[r * 256 + tid] + (float)b[r * 256 + tid];
    red[tid] = cs; __syncthreads();
    for (int off = 128; off > 0; off >>= 1) {
        if (tid < off) red[tid] = fmaxf(red[tid], red[tid + off]);
        __syncthreads();
    }
    if (tid == 0) atomicMax((int*)&stats[1], __float_as_int(red[0]));
}

// ---------------- z0 = attn2^T / colsum_max, hi/lo planes ----------------
__global__ __launch_bounds__(256) void k_z0(const __bf16* __restrict__ ph,
        const __bf16* __restrict__ pl, const float* __restrict__ stats,
        __bf16* __restrict__ zh, __bf16* __restrict__ zl) {
    int idx = blockIdx.x * 256 + threadIdx.x;
    int bh = idx >> 16, r = (idx >> 8) & 255, c = idx & 255;
    float inv = 1.f / (stats[0] * stats[1]);
    size_t src = ((size_t)bh << 16) + (size_t)c * 256 + r;
    float v = ((float)ph[src] + (float)pl[src]) * inv;
    __bf16 hh = (__bf16)v;
    zh[idx] = hh;
    zl[idx] = (__bf16)(v - (float)hh);
}

// ---------------- plane GEMM core: LDS-staged (gload16 + XOR swizzle) ----------
// 64x64 tile, K=256 in 4 steps; A,B hi/lo planes; B^T-rows = rows of B plane
// (symmetric B, or pre-transposed planes). 24 MFMA/wave/k-step, no staging VALU.
__device__ __forceinline__ void pgemm_core(const __bf16* __restrict__ Ah,
        const __bf16* __restrict__ Al, const __bf16* __restrict__ Bth,
        const __bf16* __restrict__ Btl, int m0, int n0,
        __bf16* sAh, __bf16* sAl, __bf16* sBh, __bf16* sBl, f32x4 acc[2][2]) {
    int tid = threadIdx.x;
    int wave = tid >> 6, l = tid & 63, lm = l & 15, lq = l >> 4;
    int wm = wave & 1, wn = wave >> 1;
    int lr = l >> 3, lc8 = l & 7;
    int src_c = (lc8 ^ lr) * 8;
    for (int k0 = 0; k0 < 256; k0 += 64) {
        #pragma unroll
        for (int i = 0; i < 2; ++i) {
            int g = wave * 2 + i;        // 8-row group (8 groups of 8 rows)
            size_t ra = (size_t)(m0 + g * 8 + lr) * 256 + k0 + src_c;
            size_t rb = (size_t)(n0 + g * 8 + lr) * 256 + k0 + src_c;
            gload16(&Ah[ra], &sAh[g * 512]);
            gload16(&Al[ra], &sAl[g * 512]);
            gload16(&Bth[rb], &sBh[g * 512]);
            gload16(&Btl[rb], &sBl[g * 512]);
        }
        __syncthreads();
        #pragma unroll
        for (int ko = 0; ko < 2; ++ko) {
            int ch = (ko << 2) | lq;
            bf16x8 ah[2], al2[2], bh2[2], bl2[2];
            #pragma unroll
            for (int mi = 0; mi < 2; ++mi) {
                int r = wm * 32 + mi * 16 + lm;
                int o = r * 64 + ((ch ^ (r & 7)) << 3);
                ah[mi]  = *(bf16x8*)&sAh[o];
                al2[mi] = *(bf16x8*)&sAl[o];
            }
            #pragma unroll
            for (int ni = 0; ni < 2; ++ni) {
                int r = wn * 32 + ni * 16 + lm;
                int o = r * 64 + ((ch ^ (r & 7)) << 3);
                bh2[ni] = *(bf16x8*)&sBh[o];
                bl2[ni] = *(bf16x8*)&sBl[o];
            }
            #pragma unroll
            for (int mi = 0; mi < 2; ++mi)
                #pragma unroll
                for (int ni = 0; ni < 2; ++ni) {
                    acc[mi][ni] = mfma_bf16(ah[mi], bh2[ni], acc[mi][ni]);
                    acc[mi][ni] = mfma_bf16(ah[mi], bl2[ni], acc[mi][ni]);
                    acc[mi][ni] = mfma_bf16(al2[mi], bh2[ni], acc[mi][ni]);
                }
        }
        __syncthreads();
    }
}

// Out = delta*I + alpha'*(A@B) + beta*Cin, alpha' = alpha/(s0*s1) if sPtr.
// outMode 0: hi/lo planes; outMode 1: bf16 slot-permuted zt2t. grid (4,N/64,32).
__global__ __launch_bounds__(256) void k_pgemm(const __bf16* __restrict__ Ah,
        const __bf16* __restrict__ Al, const __bf16* __restrict__ Bth,
        const __bf16* __restrict__ Btl, const __bf16* __restrict__ Ch,
        const __bf16* __restrict__ Cl, __bf16* __restrict__ OutH,
        __bf16* __restrict__ OutL, float alpha, const float* __restrict__ sPtr,
        float beta, float delta, int outMode, long bStride) {
    __shared__ __bf16 sAh[64 * 64], sAl[64 * 64], sBh[64 * 64], sBl[64 * 64];
    int tid = threadIdx.x;
    int wave = tid >> 6, l = tid & 63, lm = l & 15, lq = l >> 4;
    int wm = wave & 1, wn = wave >> 1;
    int bh = blockIdx.z;
    int m0 = blockIdx.x * 64, n0 = blockIdx.y * 64;
    float aEff = alpha;
    if (sPtr) aEff *= 1.f / (sPtr[0] * sPtr[1]);
    f32x4 acc[2][2] = {};
    pgemm_core(Ah + (size_t)bh * 65536, Al + (size_t)bh * 65536,
               Bth + (size_t)bh * bStride, Btl + (size_t)bh * bStride,
               m0, n0, sAh, sAl, sBh, sBl, acc);
    #pragma unroll
    for (int mi = 0; mi < 2; ++mi)
    #pragma unroll
    for (int ni = 0; ni < 2; ++ni)
    #pragma unroll
    for (int reg = 0; reg < 4; ++reg) {
        int gr = m0 + wm * 32 + mi * 16 + lq * 4 + reg;
        int gc = n0 + wn * 32 + ni * 16 + lm;
        float v = aEff * acc[mi][ni][reg];
        if (beta != 0.f) {
            size_t ci = (size_t)bh * 65536 + (size_t)gr * 256 + gc;
            v += beta * ((float)Ch[ci] + (float)Cl[ci]);
        }
        if (gr == gc) v += delta;
        if (outMode == 0) {
            size_t di = (size_t)bh * 65536 + (size_t)gr * 256 + gc;
            __bf16 hh = (__bf16)v;
            OutH[di] = hh;
            OutL[di] = (__bf16)(v - (float)hh);
        } else {
            int ci2 = gr >> 4, lqm = (gr >> 2) & 3, r = gr & 3;
            int slot = ((ci2 >> 1) << 5) + (lqm << 3) + ((ci2 & 1) << 2) + r;
            OutH[(size_t)bh * 16384 + (size_t)gc * 256 + slot] = (__bf16)v;
        }
    }
}

// dual update: z' = 0.25 z@W3 (z<32) and A' = 0.25 A@W3 (z>=32), hi/lo planes
__global__ __launch_bounds__(256) void k_pgemm_dual(const __bf16* __restrict__ Zh,
        const __bf16* __restrict__ Zl, const __bf16* __restrict__ A2h,
        const __bf16* __restrict__ A2l, const __bf16* __restrict__ Bth,
        const __bf16* __restrict__ Btl, __bf16* __restrict__ OzH,
        __bf16* __restrict__ OzL, __bf16* __restrict__ OaH, __bf16* __restrict__ OaL) {
    __shared__ __bf16 sAh[64 * 64], sAl[64 * 64], sBh[64 * 64], sBl[64 * 64];
    int tid = threadIdx.x;
    int wave = tid >> 6, l = tid & 63, lm = l & 15, lq = l >> 4;
    int wm = wave & 1, wn = wave >> 1;
    int zz = blockIdx.z, bh = zz & 31;
    const __bf16* Lh = (zz >= 32 ? A2h : Zh) + (size_t)bh * 65536;
    const __bf16* Ll = (zz >= 32 ? A2l : Zl) + (size_t)bh * 65536;
    __bf16* Oh = (zz >= 32 ? OaH : OzH) + (size_t)bh * 65536;
    __bf16* Ol = (zz >= 32 ? OaL : OzL) + (size_t)bh * 65536;
    int m0 = blockIdx.x * 64, n0 = blockIdx.y * 64;
    f32x4 acc[2][2] = {};
    pgemm_core(Lh, Ll, Bth + (size_t)bh * 65536, Btl + (size_t)bh * 65536,
               m0, n0, sAh, sAl, sBh, sBl, acc);
    #pragma unroll
    for (int mi = 0; mi < 2; ++mi)
    #pragma unroll
    for (int ni = 0; ni < 2; ++ni)
    #pragma unroll
    for (int reg = 0; reg < 4; ++reg) {
        int gr = m0 + wm * 32 + mi * 16 + lq * 4 + reg;
        int gc = n0 + wn * 32 + ni * 16 + lm;
        float v = 0.25f * acc[mi][ni][reg];
        __bf16 hh = (__bf16)v;
        Oh[(size_t)gr * 256 + gc] = hh;
        Ol[(size_t)gr * 256 + gc] = (__bf16)(v - (float)hh);
    }
}

// ---------------- attn3 flash, swapped QK^T, P fully in-register (no LDS) ----------------
__global__ __launch_bounds__(256) void k_attn3(const __bf16* __restrict__ ql,
        const __bf16* __restrict__ kk, const __bf16* __restrict__ vt,
        float* __restrict__ O_s, float* __restrict__ l_s) {
    int tid = threadIdx.x;
    int wave = tid >> 6, l = tid & 63, lm = l & 15, lq = l >> 4;
    int s = blockIdx.x, bh = blockIdx.y;
    const __bf16* qb = ql + (size_t)bh * 16384;
    bf16x8 qa[4][2];
    #pragma unroll
    for (int mi = 0; mi < 4; ++mi)
        #pragma unroll
        for (int ko = 0; ko < 2; ++ko)
            qa[mi][ko] = *(const bf16x8*)&qb[(size_t)(wave * 64 + mi * 16 + lm) * 64 + ko * 32 + lq * 8];
    f32x4 O[4][4] = {};
    float lsum[4] = {};
    for (int it = 0; it < 8; ++it) {
        int c0 = s * 512 + it * 64;
        bf16x8 kf[4][2];
        #pragma unroll
        for (int ci = 0; ci < 4; ++ci)
            #pragma unroll
            for (int ko = 0; ko < 2; ++ko)
                kf[ci][ko] = *(const bf16x8*)&kk[((size_t)bh * 8192 + c0 + ci * 16 + lm) * 64 + ko * 32 + lq * 8];
        f32x4 St[4][4] = {};
        #pragma unroll
        for (int ci = 0; ci < 4; ++ci)
            #pragma unroll
            for (int ko = 0; ko < 2; ++ko)
                #pragma unroll
                for (int mi = 0; mi < 4; ++mi)
                    St[mi][ci] = mfma_bf16(kf[ci][ko], qa[mi][ko], St[mi][ci]);
        bf16x4 pk[4][4];
        #pragma unroll
        for (int mi = 0; mi < 4; ++mi)
            #pragma unroll
            for (int ci = 0; ci < 4; ++ci)
                #pragma unroll
                for (int reg = 0; reg < 4; ++reg) {
                    float e = __expf(St[mi][ci][reg]);
                    lsum[mi] += e;
                    pk[mi][ci][reg] = (__bf16)e;
                }
        #pragma unroll
        for (int ko = 0; ko < 2; ++ko) {
            bf16x8 af[4];
            #pragma unroll
            for (int mi = 0; mi < 4; ++mi)
                #pragma unroll
                for (int r = 0; r < 4; ++r) {
                    af[mi][r]     = pk[mi][2 * ko][r];
                    af[mi][4 + r] = pk[mi][2 * ko + 1][r];
                }
            #pragma unroll
            for (int ni = 0; ni < 4; ++ni) {
                const __bf16* vrow = &vt[((size_t)bh * 64 + ni * 16 + lm) * 8192 + c0 + ko * 32 + lq * 4];
                bf16x4 v0 = *(const bf16x4*)&vrow[0];
                bf16x4 v1 = *(const bf16x4*)&vrow[16];
                bf16x8 vb;
                #pragma unroll
                for (int r = 0; r < 4; ++r) { vb[r] = v0[r]; vb[4 + r] = v1[r]; }
                #pragma unroll
                for (int mi = 0; mi < 4; ++mi)
                    O[mi][ni] = mfma_bf16(af[mi], vb, O[mi][ni]);
            }
        }
    }
    #pragma unroll
    for (int mi = 0; mi < 4; ++mi) {
        float v = lsum[mi];
        v += __shfl_xor(v, 16);
        v += __shfl_xor(v, 32);
        lsum[mi] = v;
    }
    int base = (bh * 16 + s) * 256;
    #pragma unroll
    for (int mi = 0; mi < 4; ++mi)
        if (lq == 0) l_s[base + wave * 64 + mi * 16 + lm] = lsum[mi];
    #pragma unroll
    for (int mi = 0; mi < 4; ++mi)
        #pragma unroll
        for (int reg = 0; reg < 4; ++reg) {
            int r = wave * 64 + mi * 16 + lq * 4 + reg;
            #pragma unroll
            for (int ni = 0; ni < 4; ++ni)
                O_s[((size_t)(base + r)) * 64 + ni * 16 + lm] = O[mi][ni][reg];
        }
}

// ---------------- combine attn3 splits -> t2^T hi/lo planes ----------------
__global__ __launch_bounds__(256) void k_t2combine(const float* __restrict__ O_s,
        const float* __restrict__ l_s, __bf16* __restrict__ t2th,
        __bf16* __restrict__ t2tl) {
    int idx = blockIdx.x * 256 + threadIdx.x;  // 524288
    int bh = idx >> 14, r = (idx >> 6) & 255, d = idx & 63;
    float den = 0.f, num = 0.f;
    #pragma unroll
    for (int s = 0; s < 16; ++s) {
        int b2 = (bh * 16 + s) * 256 + r;
        den += l_s[b2];
        num += O_s[(size_t)b2 * 64 + d];
    }
    float v = num / den;
    __bf16 hh = (__bf16)v;
    size_t di = ((size_t)bh * 64 + d) * 256 + r;   // transposed: [bh][d][r]
    t2th[di] = hh;
    t2tl[di] = (__bf16)(v - (float)hh);
}

// ---------------- depthwise residual conv over n: convb(bh,n,d) = conv(vt) ----------------
__global__ __launch_bounds__(256) void k_conv(const __bf16* __restrict__ vt,
        const float* __restrict__ resk, __bf16* __restrict__ convb) {
    int bh = blockIdx.y, h = bh & 7;
    int d = threadIdx.x & 63, tg = threadIdx.x >> 6;
    int t0 = blockIdx.x * 64 + tg * 16;
    __shared__ float kfs[33];
    if (threadIdx.x < 33) kfs[threadIdx.x] = resk[h * 33 + threadIdx.x];
    __syncthreads();
    const __bf16* row = vt + ((size_t)bh * 64 + d) * 8192;
    float win[48];
    #pragma unroll
    for (int c = 0; c < 6; ++c) {
        int tok0 = t0 - 16 + c * 8;
        if (tok0 >= 0 && tok0 + 7 < 8192) {
            bf16x8 v8 = *(const bf16x8*)&row[tok0];
            #pragma unroll
            for (int e = 0; e < 8; ++e) win[c * 8 + e] = (float)v8[e];
        } else {
            #pragma unroll
            for (int e = 0; e < 8; ++e) {
                int tok = tok0 + e;
                win[c * 8 + e] = (tok >= 0 && tok < 8192) ? (float)row[tok] : 0.f;
            }
        }
    }
    float o[16];
    #pragma unroll
    for (int i = 0; i < 16; ++i) o[i] = 0.f;
    #pragma unroll
    for (int j = 0; j < 33; ++j) {
        float kf = kfs[j];
        #pragma unroll
        for (int i = 0; i < 16; ++i) o[i] += kf * win[i + j];
    }
    __bf16* outr = convb + ((size_t)bh * 8192) * 64 + d;
    #pragma unroll
    for (int i = 0; i < 16; ++i)
        outr[(size_t)(t0 + i) * 64] = (__bf16)o[i];
}

// ---------------- attn1 fused: softmax(q k_l^T) @ zt2 + convb ----------------
// 64 rows/wave: kf/zfr loads amortized over 4 mi sub-tiles. Unnormalized
// accumulation; exact per-row 1/rowsum fetched via shfl. Zero LDS.
__global__ __launch_bounds__(256) void k_attn1(const __bf16* __restrict__ q,
        const __bf16* __restrict__ kl, const __bf16* __restrict__ zt2p,
        const __bf16* __restrict__ convb, __bf16* __restrict__ outp) {
    int tid = threadIdx.x;
    int wave = tid >> 6, l = tid & 63, lm = l & 15, lq = l >> 4;
    int bh = blockIdx.y;
    int t0 = blockIdx.x * 256;
    int b = bh >> 3, h = bh & 7;
    const __bf16* qb = q + (size_t)bh * 8192 * 64;
    const __bf16* kb = kl + (size_t)bh * 16384;
    const __bf16* zb = zt2p + (size_t)bh * 16384;
    int rowb = t0 + wave * 64;
    bf16x8 qa[4][2];
    #pragma unroll
    for (int mi = 0; mi < 4; ++mi)
        #pragma unroll
        for (int ko = 0; ko < 2; ++ko)
            qa[mi][ko] = *(const bf16x8*)&qb[(size_t)(rowb + mi * 16 + lm) * 64 + ko * 32 + lq * 8];
    f32x4 O[4][4] = {};
    float rs[4] = {};
    #pragma unroll
    for (int c2 = 0; c2 < 8; ++c2) {       // 2 landmark-col blocks per chunk
        bf16x8 kf[2][2];
        #pragma unroll
        for (int ci = 0; ci < 2; ++ci)
            #pragma unroll
            for (int ko = 0; ko < 2; ++ko)
                kf[ci][ko] = *(const bf16x8*)&kb[(size_t)((c2 * 2 + ci) * 16 + lm) * 64 + ko * 32 + lq * 8];
        f32x4 St[4][2] = {};
        #pragma unroll
        for (int ci = 0; ci < 2; ++ci)
            #pragma unroll
            for (int ko = 0; ko < 2; ++ko)
                #pragma unroll
                for (int mi = 0; mi < 4; ++mi)
                    St[mi][ci] = mfma_bf16(kf[ci][ko], qa[mi][ko], St[mi][ci]);
        bf16x4 pk[4][2];
        #pragma unroll
        for (int mi = 0; mi < 4; ++mi)
            #pragma unroll
            for (int ci = 0; ci < 2; ++ci)
                #pragma unroll
                for (int reg = 0; reg < 4; ++reg) {
                    float e = __expf(St[mi][ci][reg]);
                    rs[mi] += e;
                    pk[mi][ci][reg] = (__bf16)e;
                }
        bf16x8 zfr[4];
        #pragma unroll
        for (int ni = 0; ni < 4; ++ni)
            zfr[ni] = *(const bf16x8*)&zb[(size_t)(ni * 16 + lm) * 256 + c2 * 32 + lq * 8];
        #pragma unroll
        for (int mi = 0; mi < 4; ++mi) {
            bf16x8 af;
            #pragma unroll
            for (int r = 0; r < 4; ++r) {
                af[r]     = pk[mi][0][r];
                af[4 + r] = pk[mi][1][r];
            }
            #pragma unroll
            for (int ni = 0; ni < 4; ++ni)
                O[mi][ni] = mfma_bf16(af, zfr[ni], O[mi][ni]);
        }
    }
    #pragma unroll
    for (int mi = 0; mi < 4; ++mi) {
        float v = rs[mi];
        v += __shfl_xor(v, 16);
        v += __shfl_xor(v, 32);            // rowsum(rowb+mi*16+lm) on all lq-copies
        float invr[4];
        #pragma unroll
        for (int reg = 0; reg < 4; ++reg)
            invr[reg] = 1.f / __shfl(v, lq * 4 + reg);
        #pragma unroll
        for (int ni = 0; ni < 4; ++ni)
            #pragma unroll
            for (int reg = 0; reg < 4; ++reg) {
                int tok = rowb + mi * 16 + lq * 4 + reg;
                int d = ni * 16 + lm;
                float conv = (float)convb[((size_t)bh * 8192 + tok) * 64 + d];
                float val = O[mi][ni][reg] * invr[reg] + conv;
                outp[((size_t)(b * 8192 + tok)) * 512 + h * 64 + d] = (__bf16)val;
            }
    }
}

// ---------------- launcher ----------------
extern "C" void kernel_launch(void* const* d_in, const int* in_sizes, int n_in,
                              void* d_out, int out_size, void* d_ws, size_t ws_size,
                              hipStream_t stream) {
    const float* x    = (const float*)d_in[0];
    const float* wqkv = (const float*)d_in[1];
    const float* wout = (const float*)d_in[2];
    const float* bout = (const float*)d_in[3];
    const float* resk = (const float*)d_in[4];
    char* ws = (char*)d_ws;
    size_t off = 0;
    auto alloc = [&](size_t bytes) {
        char* p = ws + off;
        off += (bytes + 255) & ~(size_t)255;
        return p;
    };
    const size_t PL = 2097152;                   // elems per 4MB bf16 plane (32x256x256)
    __bf16* q_bf   = (__bf16*)alloc(33554432);   // (bh,n,d)
    __bf16* k_bf   = (__bf16*)alloc(33554432);   // (bh,n,d)
    __bf16* vt     = (__bf16*)alloc(33554432);   // (bh,d,n)
    __bf16* outpre = (__bf16*)alloc(33554432);   // v_tmp early, attn1 out later
    __bf16* q_l    = (__bf16*)alloc(1048576);
    __bf16* k_l    = (__bf16*)alloc(1048576);
    __bf16* a2h    = (__bf16*)alloc(8388608);    // attn2 hi/lo planes; An slot later
    __bf16* zAh    = (__bf16*)alloc(8388608);
    __bf16* zBh    = (__bf16*)alloc(8388608);
    __bf16* Amh    = (__bf16*)alloc(8388608);
    __bf16* W2h    = (__bf16*)alloc(8388608);
    __bf16* W3h    = (__bf16*)alloc(8388608);
    float*  O_s    = (float*)alloc(33554432);    // xb early, attn3 out, convb late
    float*  l_s    = (float*)alloc(524288);
    __bf16* t2th   = (__bf16*)alloc(2097152);    // t2^T hi/lo planes (1MB each)
    __bf16* zt2t   = (__bf16*)alloc(1048576);
    __bf16* wqkvt  = (__bf16*)alloc(1572864);
    __bf16* woutt  = (__bf16*)alloc(524288);
    float*  stats  = (float*)alloc(256);
    __bf16* convb  = (__bf16*)O_s;               // alias (32 MB <= 33.5 MB)
    __bf16* xb     = (__bf16*)O_s;               // alias: x bf16, dead before attn3
    __bf16* a2l = a2h + PL;
    __bf16* zAl = zAh + PL;
    __bf16* zBl = zBh + PL;
    __bf16* Aml = Amh + PL;
    __bf16* W2l = W2h + PL;
    __bf16* W3l = W3h + PL;
    __bf16* t2tl = t2th + 524288;

    k_init_stats<<<1, 1, 0, stream>>>(stats);
    k_cvt<<<8192, 256, 0, stream>>>(x, xb);
    k_transpose_f32<<<dim3(8, 24), 256, 0, stream>>>(wqkv, wqkvt, 512, 1536);
    k_transpose_f32<<<dim3(8, 8), 256, 0, stream>>>(wout, woutt, 512, 512);
    k_gemm_big<0><<<dim3(256, 12), 256, 0, stream>>>(xb, wqkvt, 512,
            q_bf, k_bf, outpre, nullptr, nullptr);
    k_transpose_bf<<<dim3(128, 1, 32), 256, 0, stream>>>(outpre, vt, 8192, 64, 524288, 524288);
    k_landmarks<<<4096, 256, 0, stream>>>(q_bf, k_bf, q_l, k_l);
    k_attn2<<<dim3(4, 32), 256, 0, stream>>>(q_l, k_l, a2h, a2l);
    k_stats<<<32, 256, 0, stream>>>(a2h, a2l, stats);
    k_z0<<<8192, 256, 0, stream>>>(a2h, a2l, stats, zAh, zAl);
    k_attn3<<<dim3(16, 32), 256, 0, stream>>>(q_l, k_bf, vt, O_s, l_s);
    k_t2combine<<<2048, 256, 0, stream>>>(O_s, l_s, t2th, t2tl);
    k_conv<<<dim3(128, 32), 256, 0, stream>>>(vt, resk, convb);
    // A0 = s*(attn2 @ attn2^T)  (z0 = s*attn2^T -> B^T rows = s * attn2 rows)
    k_pgemm<<<dim3(4, 4, 32), 256, 0, stream>>>(a2h, a2l, a2h, a2l,
            nullptr, nullptr, Amh, Aml, 1.f, stats, 0.f, 0.f, 0, 65536);
    __bf16 *zch = zAh, *zcl = zAl, *znh = zBh, *znl = zBl;
    __bf16 *Ach = Amh, *Acl = Aml, *Anh = a2h, *Anl = a2l;   // attn2 planes dead after A0
    for (int it = 0; it < 6; ++it) {
        k_pgemm<<<dim3(4, 4, 32), 256, 0, stream>>>(Ach, Acl, Ach, Acl,
                Ach, Acl, W2h, W2l, 1.f, nullptr, -7.f, 15.f, 0, 65536);  // W2 = 15I - 7A + A@A
        k_pgemm<<<dim3(4, 4, 32), 256, 0, stream>>>(Ach, Acl, W2h, W2l,
                nullptr, nullptr, W3h, W3l, -1.f, nullptr, 0.f, 13.f, 0, 65536); // W3 = 13I - A@W2
        if (it < 5) {
            k_pgemm_dual<<<dim3(4, 4, 64), 256, 0, stream>>>(zch, zcl, Ach, Acl,
                    W3h, W3l, znh, znl, Anh, Anl);
            __bf16* t;
            t = Ach; Ach = Anh; Anh = t;
            t = Acl; Acl = Anl; Anl = t;
        } else {
            k_pgemm_dual<<<dim3(4, 4, 32), 256, 0, stream>>>(zch, zcl, zch, zcl,
                    W3h, W3l, znh, znl, znh, znl);
        }
        __bf16* t;
        t = zch; zch = znh; znh = t;
        t = zcl; zcl = znl; znl = t;
    }
    // zt2t[bh][d][slot] = (z_final @ t2)^T, bf16, slot-permuted for attn1's PV
    k_pgemm<<<dim3(4, 1, 32), 256, 0, stream>>>(zch, zcl, t2th, t2tl,
            nullptr, nullptr, zt2t, nullptr, 1.f, nullptr, 0.f, 0.f, 1, 16384);
    k_attn1<<<dim3(32, 32), 256, 0, stream>>>(q_bf, k_l, zt2t, convb, outpre);
    k_gemm_big<1><<<dim3(256, 4), 256, 0, stream>>>(outpre, woutt, 512,
            nullptr, nullptr, nullptr, (float*)d_out, bout);
}